// Round 7
// baseline (426.174 us; speedup 1.0000x reference)
//
#include <hip/hip_runtime.h>

// GCN 2-layer + edge dot decoder. Dims fixed: in=512, hid=128, out=64.
#define IN_C  512
#define HID_C 128
#define OUT_C 64

using short8 = __attribute__((ext_vector_type(8))) short;   // 8 bf16
using floatx4 = __attribute__((ext_vector_type(4))) float;  // mfma acc

__device__ inline unsigned short f2bf(float f) {  // RNE
    unsigned u = __builtin_bit_cast(unsigned, f);
    u += 0x7FFFu + ((u >> 16) & 1u);
    return (unsigned short)(u >> 16);
}
__device__ inline float bf2f(unsigned short h) {
    unsigned u = ((unsigned)h) << 16;
    return __builtin_bit_cast(float, u);
}
__device__ inline unsigned short f2h(float f) {  // fp32 -> fp16 RNE
    _Float16 h = (_Float16)f;
    return __builtin_bit_cast(unsigned short, h);
}
__device__ inline float h2f(unsigned v) {  // low 16 bits = fp16
    return (float)__builtin_bit_cast(_Float16, (unsigned short)v);
}

// ---------------- CSR build ----------------
__global__ void k_zero_int(int* __restrict__ p, int n) {
    int i = blockIdx.x * blockDim.x + threadIdx.x;
    if (i < n) p[i] = 0;
}

__global__ void k_count(const int* __restrict__ dst, int* __restrict__ cnt, int e) {
    int i = blockIdx.x * blockDim.x + threadIdx.x;
    if (i < e) atomicAdd(&cnt[dst[i]], 1);
}

// block-sum of cnt + dinv computed in the same pass (cnt is final here)
__global__ void k_blocksum_dinv(const int* __restrict__ cnt, int* __restrict__ bsum,
                                float* __restrict__ dinv, int n) {
    __shared__ int sdata[256];
    int t = threadIdx.x;
    int i = blockIdx.x * 256 + t;
    int c = (i < n) ? cnt[i] : 0;
    if (i < n) dinv[i] = rsqrtf(1.0f + (float)c);  // +1 self-loop
    sdata[t] = c;
    __syncthreads();
    for (int s = 128; s > 0; s >>= 1) {
        if (t < s) sdata[t] += sdata[t + s];
        __syncthreads();
    }
    if (t == 0) bsum[blockIdx.x] = sdata[0];
}

__global__ void k_scanpartials(int* __restrict__ bsum, int nb) {
    __shared__ int sdata[256];
    int t = threadIdx.x;
    int orig = (t < nb) ? bsum[t] : 0;
    sdata[t] = orig;
    __syncthreads();
    for (int off = 1; off < 256; off <<= 1) {
        int v = (t >= off) ? sdata[t - off] : 0;
        __syncthreads();
        sdata[t] += v;
        __syncthreads();
    }
    if (t < nb) bsum[t] = sdata[t] - orig;  // exclusive
}

__global__ void k_scanfinal(const int* __restrict__ cnt, const int* __restrict__ bsum_ex,
                            int* __restrict__ row_ptr, int n, int e_total) {
    __shared__ int sdata[256];
    int t = threadIdx.x;
    int i = blockIdx.x * 256 + t;
    int orig = (i < n) ? cnt[i] : 0;
    sdata[t] = orig;
    __syncthreads();
    for (int off = 1; off < 256; off <<= 1) {
        int v = (t >= off) ? sdata[t - off] : 0;
        __syncthreads();
        sdata[t] += v;
        __syncthreads();
    }
    if (i < n) row_ptr[i] = sdata[t] - orig + bsum_ex[blockIdx.x];
    if (i == 0) row_ptr[n] = e_total;
}

// destructive fill: consumes cnt as a down-counter (cnt no longer needed after)
__global__ void k_fill(const int* __restrict__ src, const int* __restrict__ dst,
                       const int* __restrict__ row_ptr, int* __restrict__ cnt,
                       int* __restrict__ col, int e) {
    int i = blockIdx.x * blockDim.x + threadIdx.x;
    if (i < e) {
        int d = dst[i];
        int pos = atomicSub(&cnt[d], 1) - 1;  // unique slot in [0, deg)
        col[row_ptr[d] + pos] = src[i];
    }
}

// ---------------- weight prep (both layers in one launch) ----------------
__global__ void k_prep_w2(const float* __restrict__ W1, unsigned short* __restrict__ hi1,
                          unsigned short* __restrict__ lo1, const float* __restrict__ W2,
                          unsigned short* __restrict__ hi2, unsigned short* __restrict__ lo2) {
    int i = blockIdx.x * blockDim.x + threadIdx.x;
    if (i < IN_C * HID_C) {
        int k = i / HID_C, n = i % HID_C;
        float v = W1[i];
        unsigned short h = f2bf(v);
        hi1[(long)n * IN_C + k] = h;
        lo1[(long)n * IN_C + k] = f2bf(v - bf2f(h));
    } else if (i < IN_C * HID_C + HID_C * OUT_C) {
        int j = i - IN_C * HID_C;
        int k = j / OUT_C, n = j % OUT_C;
        float v = W2[j];
        unsigned short h = f2bf(v);
        hi2[(long)n * HID_C + k] = h;
        lo2[(long)n * HID_C + k] = f2bf(v - bf2f(h));
    }
}

// ---------------- split-bf16 MFMA GEMM (R4 structure — best measured, 73 us) --------
// Register-prefetch + LDS double-buffer, one __syncthreads per 64-k tile. Locked:
// five structural variants all landed 73-86 us (memory-system floor for this pattern).
// Epilogue writes h in CHANNEL-SLICED fp16 layout: slice s = channels [32s, 32s+32),
// stored as [s][node][32] -- each slice table is 3.2 MB and fits per-XCD L2, which
// makes the downstream random gathers L2-resident.
template <int K, int NPW>
__global__ __launch_bounds__(256) void k_gemm_mfma(
    const float* __restrict__ A, const unsigned short* __restrict__ Bt_hi,
    const unsigned short* __restrict__ Bt_lo, const float* __restrict__ dinv,
    unsigned short* __restrict__ Hs, int M) {
    constexpr int N = 64 * NPW;
    constexpr int LDA = 72;       // shorts; 144 B rows: frag b128 reads land 2-way (free)
    constexpr int NT = K / 64;    // number of 64-k tiles
    __shared__ __align__(16) unsigned short As_hi[2][64 * LDA];
    __shared__ __align__(16) unsigned short As_lo[2][64 * LDA];

    const int tid = threadIdx.x;
    const int w = tid >> 6;
    const int lane = tid & 63;
    const int m = lane & 15;
    const int quad = lane >> 4;
    const int m0 = blockIdx.x * 64;

    // staging coords: thread handles rows srow+16i, fixed 4-float column skk
    const int srow = tid >> 4;
    const int skk = (tid & 15) << 2;

    floatx4 acc[4][NPW];
#pragma unroll
    for (int mi = 0; mi < 4; ++mi)
#pragma unroll
        for (int ni = 0; ni < NPW; ++ni) acc[mi][ni] = (floatx4){0.f, 0.f, 0.f, 0.f};

    float4 pf[4];
    // prologue: load + convert tile 0 into buf 0
#pragma unroll
    for (int i = 0; i < 4; ++i) {
        int gm = m0 + srow + 16 * i;
        pf[i] = make_float4(0.f, 0.f, 0.f, 0.f);
        if (gm < M) pf[i] = *(const float4*)&A[(long)gm * K + skk];
    }
#pragma unroll
    for (int i = 0; i < 4; ++i) {
        ushort4 h, l;
        h.x = f2bf(pf[i].x); l.x = f2bf(pf[i].x - bf2f(h.x));
        h.y = f2bf(pf[i].y); l.y = f2bf(pf[i].y - bf2f(h.y));
        h.z = f2bf(pf[i].z); l.z = f2bf(pf[i].z - bf2f(h.z));
        h.w = f2bf(pf[i].w); l.w = f2bf(pf[i].w - bf2f(h.w));
        int off = (srow + 16 * i) * LDA + skk;
        *(ushort4*)&As_hi[0][off] = h;
        *(ushort4*)&As_lo[0][off] = l;
    }

    for (int t = 0; t < NT; ++t) {
        __syncthreads();  // buf[t&1] fully written; prior readers of buf[(t+1)&1] done
        const int buf = t & 1;
        // prefetch next tile into registers (latency overlaps compute below)
        if (t + 1 < NT) {
#pragma unroll
            for (int i = 0; i < 4; ++i) {
                int gm = m0 + srow + 16 * i;
                pf[i] = make_float4(0.f, 0.f, 0.f, 0.f);
                if (gm < M) pf[i] = *(const float4*)&A[(long)gm * K + (t + 1) * 64 + skk];
            }
        }
        // compute from buf
#pragma unroll
        for (int s = 0; s < 2; ++s) {
            short8 ah[4], al[4];
#pragma unroll
            for (int mi = 0; mi < 4; ++mi) {
                int off = (mi * 16 + m) * LDA + s * 32 + quad * 8;
                ah[mi] = *(const short8*)&As_hi[buf][off];
                al[mi] = *(const short8*)&As_lo[buf][off];
            }
#pragma unroll
            for (int ni = 0; ni < NPW; ++ni) {
                int n = (w * NPW + ni) * 16 + m;
                long boff = (long)n * K + t * 64 + s * 32 + quad * 8;
                short8 bh = *(const short8*)&Bt_hi[boff];
                short8 bl = *(const short8*)&Bt_lo[boff];
#pragma unroll
                for (int mi = 0; mi < 4; ++mi) {
                    acc[mi][ni] = __builtin_amdgcn_mfma_f32_16x16x32_bf16(ah[mi], bh, acc[mi][ni], 0, 0, 0);
                    acc[mi][ni] = __builtin_amdgcn_mfma_f32_16x16x32_bf16(ah[mi], bl, acc[mi][ni], 0, 0, 0);
                    acc[mi][ni] = __builtin_amdgcn_mfma_f32_16x16x32_bf16(al[mi], bh, acc[mi][ni], 0, 0, 0);
                }
            }
        }
        // convert prefetched regs into the other buffer
        if (t + 1 < NT) {
#pragma unroll
            for (int i = 0; i < 4; ++i) {
                ushort4 h, l;
                h.x = f2bf(pf[i].x); l.x = f2bf(pf[i].x - bf2f(h.x));
                h.y = f2bf(pf[i].y); l.y = f2bf(pf[i].y - bf2f(h.y));
                h.z = f2bf(pf[i].z); l.z = f2bf(pf[i].z - bf2f(h.z));
                h.w = f2bf(pf[i].w); l.w = f2bf(pf[i].w - bf2f(h.w));
                int off = (srow + 16 * i) * LDA + skk;
                *(ushort4*)&As_hi[buf ^ 1][off] = h;
                *(ushort4*)&As_lo[buf ^ 1][off] = l;
            }
        }
    }

    // epilogue: C/D layout col=lane&15, row=quad*4+reg; scale by dinv[row];
    // fp16 store in channel-sliced layout [n>>5][row][n&31]
#pragma unroll
    for (int mi = 0; mi < 4; ++mi) {
#pragma unroll
        for (int r = 0; r < 4; ++r) {
            int row = m0 + mi * 16 + quad * 4 + r;
            if (row < M) {
                float dv = dinv[row];
#pragma unroll
                for (int ni = 0; ni < NPW; ++ni) {
                    int n = (w * NPW + ni) * 16 + m;
                    Hs[((long)(n >> 5) * M + row) * 32 + (n & 31)] = f2h(acc[mi][ni][r] * dv);
                }
            }
        }
    }
}

// ---------------- CSR aggregation: channel-sliced, L2-resident gather tables ----------
// Slice s covers channels [32s, 32s+32): table = [node][32] fp16 = 64 B/row, 3.2 MB
// total -> fits every XCD's 4 MB L2. Blocks are slice-major (slice = bid / nb), so all
// XCDs work the same slice concurrently and its table stays L2-hot.
// One node per wave; quarter q gathers edge j's 64 B row with 16 lanes x 4 B
// (2 fp16 ch/lane); 4x unroll -> 16 gathers in flight/wave. Quarters combined via
// __shfl_xor(16,32). Per-channel accumulation order identical to R6 (bitwise-same).
__global__ __launch_bounds__(256) void k_agg1(
    const unsigned short* __restrict__ h, const int* __restrict__ row_ptr,
    const int* __restrict__ col, const float* __restrict__ dinv,
    const float* __restrict__ bias, float* __restrict__ z, int n, int nb) {
    int bid = blockIdx.x;
    int s = bid / nb;                       // slice 0..3
    int node = (bid % nb) * 4 + (threadIdx.x >> 6);
    node = __builtin_amdgcn_readfirstlane(node);
    if (node >= n) return;
    int lane = threadIdx.x & 63;
    int q = lane >> 4, li = lane & 15;
    const unsigned* hp = (const unsigned*)h + (long)s * n * 16;  // 16 uints/row
    float a0 = 0.f, a1 = 0.f;
    if (q == 0) {  // self-loop once
        unsigned v = hp[(long)node * 16 + li];
        a0 = h2f(v); a1 = h2f(v >> 16);
    }
    int rs = row_ptr[node], re = row_ptr[node + 1];
    int j = rs + q;
    for (; j + 12 < re; j += 16) {  // 4 gathers in flight per quarter
        int s0 = col[j], s1 = col[j + 4], s2 = col[j + 8], s3 = col[j + 12];
        unsigned v0 = hp[(long)s0 * 16 + li];
        unsigned v1 = hp[(long)s1 * 16 + li];
        unsigned v2 = hp[(long)s2 * 16 + li];
        unsigned v3 = hp[(long)s3 * 16 + li];
        a0 += h2f(v0) + h2f(v1) + h2f(v2) + h2f(v3);
        a1 += h2f(v0 >> 16) + h2f(v1 >> 16) + h2f(v2 >> 16) + h2f(v3 >> 16);
    }
    for (; j < re; j += 4) {
        unsigned v = hp[(long)col[j] * 16 + li];
        a0 += h2f(v); a1 += h2f(v >> 16);
    }
    // combine quarters: lanes {li, li+16, li+32, li+48} hold partials of same channels
    a0 += __shfl_xor(a0, 16); a0 += __shfl_xor(a0, 32);
    a1 += __shfl_xor(a1, 16); a1 += __shfl_xor(a1, 32);
    if (q == 0) {
        float dv = dinv[node];
        float2 b = ((const float2*)bias)[s * 16 + li];
        float2 o;
        o.x = fmaxf(fmaf(a0, dv, b.x), 0.f);
        o.y = fmaxf(fmaf(a1, dv, b.y), 0.f);
        ((float2*)z)[(long)node * 64 + s * 16 + li] = o;  // z stride 128 fp32
    }
}

__global__ __launch_bounds__(256) void k_agg2(
    const unsigned short* __restrict__ h, const int* __restrict__ row_ptr,
    const int* __restrict__ col, const float* __restrict__ dinv,
    const float* __restrict__ bias, float* __restrict__ z, int n, int nb) {
    int bid = blockIdx.x;
    int s = bid / nb;                       // slice 0..1
    int node = (bid % nb) * 4 + (threadIdx.x >> 6);
    node = __builtin_amdgcn_readfirstlane(node);
    if (node >= n) return;
    int lane = threadIdx.x & 63;
    int q = lane >> 4, li = lane & 15;
    const unsigned* hp = (const unsigned*)h + (long)s * n * 16;
    float a0 = 0.f, a1 = 0.f;
    if (q == 0) {  // self-loop
        unsigned v = hp[(long)node * 16 + li];
        a0 = h2f(v); a1 = h2f(v >> 16);
    }
    int rs = row_ptr[node], re = row_ptr[node + 1];
    int j = rs + q;
    for (; j + 12 < re; j += 16) {
        int s0 = col[j], s1 = col[j + 4], s2 = col[j + 8], s3 = col[j + 12];
        unsigned v0 = hp[(long)s0 * 16 + li];
        unsigned v1 = hp[(long)s1 * 16 + li];
        unsigned v2 = hp[(long)s2 * 16 + li];
        unsigned v3 = hp[(long)s3 * 16 + li];
        a0 += h2f(v0) + h2f(v1) + h2f(v2) + h2f(v3);
        a1 += h2f(v0 >> 16) + h2f(v1 >> 16) + h2f(v2 >> 16) + h2f(v3 >> 16);
    }
    for (; j < re; j += 4) {
        unsigned v = hp[(long)col[j] * 16 + li];
        a0 += h2f(v); a1 += h2f(v >> 16);
    }
    a0 += __shfl_xor(a0, 16); a0 += __shfl_xor(a0, 32);
    a1 += __shfl_xor(a1, 16); a1 += __shfl_xor(a1, 32);
    if (q == 0) {
        float dv = dinv[node];
        float2 b = ((const float2*)bias)[s * 16 + li];
        float2 o;
        o.x = fmaf(a0, dv, b.x);
        o.y = fmaf(a1, dv, b.y);
        ((float2*)z)[(long)node * 32 + s * 16 + li] = o;  // z stride 64 fp32
    }
}

// ---------------- decoder: 4 edges per wave (quarter-wave each, float4 per lane) ------
__global__ void k_dot(const float* __restrict__ z2, const int* __restrict__ es,
                      const int* __restrict__ ed, float* __restrict__ out, int L) {
    int gid = blockIdx.x * blockDim.x + threadIdx.x;
    int wid = gid >> 6;
    int lane = threadIdx.x & 63;
    int q = lane >> 4, li = lane & 15;
    int e = wid * 4 + q;
    if (e >= L) return;
    int a = es[e], b = ed[e];
    const float4* zp = (const float4*)z2;  // 16 float4 per row (64 ch fp32)
    float4 za = zp[(long)a * 16 + li];
    float4 zb = zp[(long)b * 16 + li];
    float v = za.x * zb.x + za.y * zb.y + za.z * zb.z + za.w * zb.w;
#pragma unroll
    for (int off = 8; off > 0; off >>= 1) v += __shfl_xor(v, off);  // within quarter
    if (li == 0) out[e] = v;
}

extern "C" void kernel_launch(void* const* d_in, const int* in_sizes, int n_in,
                              void* d_out, int out_size, void* d_ws, size_t ws_size,
                              hipStream_t stream) {
    const float* x = (const float*)d_in[0];
    const int* ei = (const int*)d_in[1];
    const int* eli = (const int*)d_in[2];
    const float* W1 = (const float*)d_in[3];
    const float* b1 = (const float*)d_in[4];
    const float* W2 = (const float*)d_in[5];
    const float* b2 = (const float*)d_in[6];
    float* out = (float*)d_out;

    const int N = in_sizes[0] / IN_C;  // 50000
    const int E = in_sizes[1] / 2;     // 800000
    const int L = in_sizes[2] / 2;     // 100000
    const int* src = ei;
    const int* dst = ei + E;
    const int* es = eli;
    const int* ed = eli + L;

    const int Npad = (N + 63) & ~63;
    const int Epad = (E + 3) & ~3;

    // workspace layout
    int* cnt = (int*)d_ws;             // Npad (also the fill cursor, consumed)
    int* row_ptr = cnt + Npad;         // Npad + 64
    int* bsum = row_ptr + Npad + 64;   // 256
    int* col = bsum + 256;             // Epad
    float* dinv = (float*)(col + Epad);                   // Npad
    unsigned short* h1s = (unsigned short*)(dinv + Npad); // N*128 fp16, sliced [4][N][32]
    float* z1 = (float*)(h1s + (long)N * HID_C);          // N*128 fp32
    unsigned short* h2s = h1s;                            // alias: h1s dead after agg1; [2][N][32]
    float* z2 = z1 + (long)N * HID_C;                     // N*64 fp32
    unsigned short* wt1_hi = (unsigned short*)(z2 + (long)N * OUT_C);  // 512*128
    unsigned short* wt1_lo = wt1_hi + IN_C * HID_C;
    unsigned short* wt2_hi = wt1_lo + IN_C * HID_C;                    // 128*64
    unsigned short* wt2_lo = wt2_hi + HID_C * OUT_C;

    const int TPB = 256;
    const int nb = (N + 255) / 256;
    const int nb4 = (N + 3) / 4;

    // weight prep (both layers, one launch)
    const int PW = IN_C * HID_C + HID_C * OUT_C;
    k_prep_w2<<<(PW + TPB - 1) / TPB, TPB, 0, stream>>>(W1, wt1_hi, wt1_lo, W2, wt2_hi, wt2_lo);

    // CSR build + dinv
    k_zero_int<<<(Npad + TPB - 1) / TPB, TPB, 0, stream>>>(cnt, Npad);
    k_count<<<(E + TPB - 1) / TPB, TPB, 0, stream>>>(dst, cnt, E);
    k_blocksum_dinv<<<nb, 256, 0, stream>>>(cnt, bsum, dinv, N);
    k_scanpartials<<<1, 256, 0, stream>>>(bsum, nb);
    k_scanfinal<<<nb, 256, 0, stream>>>(cnt, bsum, row_ptr, N, E);
    k_fill<<<(E + TPB - 1) / TPB, TPB, 0, stream>>>(src, dst, row_ptr, cnt, col, E);

    // layer 1 (agg1: 4 slices, slice-major blocks)
    k_gemm_mfma<IN_C, 2><<<(N + 63) / 64, 256, 0, stream>>>(x, wt1_hi, wt1_lo, dinv, h1s, N);
    k_agg1<<<4 * nb4, 256, 0, stream>>>(h1s, row_ptr, col, dinv, b1, z1, N, nb4);

    // layer 2 (agg2: 2 slices)
    k_gemm_mfma<HID_C, 1><<<(N + 63) / 64, 256, 0, stream>>>(z1, wt2_hi, wt2_lo, dinv, h2s, N);
    k_agg2<<<2 * nb4, 256, 0, stream>>>(h2s, row_ptr, col, dinv, b2, z2, N, nb4);

    // decoder (4 edges/wave)
    k_dot<<<((long)((L + 3) / 4) * 64 + TPB - 1) / TPB, TPB, 0, stream>>>(z2, es, ed, out, L);
}

// Round 8
// 363.730 us; speedup vs baseline: 1.1717x; 1.1717x over previous
//
#include <hip/hip_runtime.h>

// GCN 2-layer + edge dot decoder. Dims fixed: in=512, hid=128, out=64.
#define IN_C  512
#define HID_C 128
#define OUT_C 64

using short8 = __attribute__((ext_vector_type(8))) short;   // 8 bf16
using floatx4 = __attribute__((ext_vector_type(4))) float;  // mfma acc

__device__ inline unsigned short f2bf(float f) {  // RNE
    unsigned u = __builtin_bit_cast(unsigned, f);
    u += 0x7FFFu + ((u >> 16) & 1u);
    return (unsigned short)(u >> 16);
}
__device__ inline float bf2f(unsigned short h) {
    unsigned u = ((unsigned)h) << 16;
    return __builtin_bit_cast(float, u);
}
__device__ inline unsigned short f2h(float f) {  // fp32 -> fp16 RNE
    _Float16 h = (_Float16)f;
    return __builtin_bit_cast(unsigned short, h);
}
__device__ inline float h2f(unsigned v) {  // low 16 bits = fp16
    return (float)__builtin_bit_cast(_Float16, (unsigned short)v);
}
__device__ inline unsigned packh2(float a, float b) {
    return (unsigned)f2h(a) | ((unsigned)f2h(b) << 16);
}

// ---------------- CSR build ----------------
__global__ void k_zero_int(int* __restrict__ p, int n) {
    int i = blockIdx.x * blockDim.x + threadIdx.x;
    if (i < n) p[i] = 0;
}

__global__ void k_count(const int* __restrict__ dst, int* __restrict__ cnt, int e) {
    int i = blockIdx.x * blockDim.x + threadIdx.x;
    if (i < e) atomicAdd(&cnt[dst[i]], 1);
}

// block-sum of cnt + dinv computed in the same pass (cnt is final here)
__global__ void k_blocksum_dinv(const int* __restrict__ cnt, int* __restrict__ bsum,
                                float* __restrict__ dinv, int n) {
    __shared__ int sdata[256];
    int t = threadIdx.x;
    int i = blockIdx.x * 256 + t;
    int c = (i < n) ? cnt[i] : 0;
    if (i < n) dinv[i] = rsqrtf(1.0f + (float)c);  // +1 self-loop
    sdata[t] = c;
    __syncthreads();
    for (int s = 128; s > 0; s >>= 1) {
        if (t < s) sdata[t] += sdata[t + s];
        __syncthreads();
    }
    if (t == 0) bsum[blockIdx.x] = sdata[0];
}

__global__ void k_scanpartials(int* __restrict__ bsum, int nb) {
    __shared__ int sdata[256];
    int t = threadIdx.x;
    int orig = (t < nb) ? bsum[t] : 0;
    sdata[t] = orig;
    __syncthreads();
    for (int off = 1; off < 256; off <<= 1) {
        int v = (t >= off) ? sdata[t - off] : 0;
        __syncthreads();
        sdata[t] += v;
        __syncthreads();
    }
    if (t < nb) bsum[t] = sdata[t] - orig;  // exclusive
}

__global__ void k_scanfinal(const int* __restrict__ cnt, const int* __restrict__ bsum_ex,
                            int* __restrict__ row_ptr, int n, int e_total) {
    __shared__ int sdata[256];
    int t = threadIdx.x;
    int i = blockIdx.x * 256 + t;
    int orig = (i < n) ? cnt[i] : 0;
    sdata[t] = orig;
    __syncthreads();
    for (int off = 1; off < 256; off <<= 1) {
        int v = (t >= off) ? sdata[t - off] : 0;
        __syncthreads();
        sdata[t] += v;
        __syncthreads();
    }
    if (i < n) row_ptr[i] = sdata[t] - orig + bsum_ex[blockIdx.x];
    if (i == 0) row_ptr[n] = e_total;
}

// destructive fill: consumes cnt as a down-counter (cnt no longer needed after)
__global__ void k_fill(const int* __restrict__ src, const int* __restrict__ dst,
                       const int* __restrict__ row_ptr, int* __restrict__ cnt,
                       int* __restrict__ col, int e) {
    int i = blockIdx.x * blockDim.x + threadIdx.x;
    if (i < e) {
        int d = dst[i];
        int pos = atomicSub(&cnt[d], 1) - 1;  // unique slot in [0, deg)
        col[row_ptr[d] + pos] = src[i];
    }
}

// ---------------- weight prep (both layers in one launch) ----------------
__global__ void k_prep_w2(const float* __restrict__ W1, unsigned short* __restrict__ hi1,
                          unsigned short* __restrict__ lo1, const float* __restrict__ W2,
                          unsigned short* __restrict__ hi2, unsigned short* __restrict__ lo2) {
    int i = blockIdx.x * blockDim.x + threadIdx.x;
    if (i < IN_C * HID_C) {
        int k = i / HID_C, n = i % HID_C;
        float v = W1[i];
        unsigned short h = f2bf(v);
        hi1[(long)n * IN_C + k] = h;
        lo1[(long)n * IN_C + k] = f2bf(v - bf2f(h));
    } else if (i < IN_C * HID_C + HID_C * OUT_C) {
        int j = i - IN_C * HID_C;
        int k = j / OUT_C, n = j % OUT_C;
        float v = W2[j];
        unsigned short h = f2bf(v);
        hi2[(long)n * HID_C + k] = h;
        lo2[(long)n * HID_C + k] = f2bf(v - bf2f(h));
    }
}

// ---------------- split-bf16 MFMA GEMM (R4 structure — locked at 73 us) --------------
// Register-prefetch + LDS double-buffer, one __syncthreads per 64-k tile.
// AH: A is fp16 (ushort) — fp16 -> split-bf16 is exact (11-bit mantissa fits 8+8),
// so the fp16 z1 path only adds z1's own rounding, not conversion error.
template <int K, int NPW, bool AH, typename AT>
__global__ __launch_bounds__(256) void k_gemm_mfma(
    const AT* __restrict__ A, const unsigned short* __restrict__ Bt_hi,
    const unsigned short* __restrict__ Bt_lo, const float* __restrict__ dinv,
    unsigned short* __restrict__ Hs, int M) {
    constexpr int N = 64 * NPW;
    constexpr int LDA = 72;       // shorts; 144 B rows: frag b128 reads land 2-way (free)
    constexpr int NT = K / 64;    // number of 64-k tiles
    __shared__ __align__(16) unsigned short As_hi[2][64 * LDA];
    __shared__ __align__(16) unsigned short As_lo[2][64 * LDA];

    const int tid = threadIdx.x;
    const int w = tid >> 6;
    const int lane = tid & 63;
    const int m = lane & 15;
    const int quad = lane >> 4;
    const int m0 = blockIdx.x * 64;

    // staging coords: thread handles rows srow+16i, fixed 4-elem column skk
    const int srow = tid >> 4;
    const int skk = (tid & 15) << 2;

    floatx4 acc[4][NPW];
#pragma unroll
    for (int mi = 0; mi < 4; ++mi)
#pragma unroll
        for (int ni = 0; ni < NPW; ++ni) acc[mi][ni] = (floatx4){0.f, 0.f, 0.f, 0.f};

    float4 pf[4];
    auto issueA = [&](int t0) {
#pragma unroll
        for (int i = 0; i < 4; ++i) {
            int gm = m0 + srow + 16 * i;
            pf[i] = make_float4(0.f, 0.f, 0.f, 0.f);
            if (gm < M) {
                if constexpr (AH) {
                    ushort4 r = *(const ushort4*)&A[(long)gm * K + t0 * 64 + skk];
                    pf[i] = make_float4(h2f(r.x), h2f(r.y), h2f(r.z), h2f(r.w));
                } else {
                    pf[i] = *(const float4*)&A[(long)gm * K + t0 * 64 + skk];
                }
            }
        }
    };
    auto convA = [&](int b) {
#pragma unroll
        for (int i = 0; i < 4; ++i) {
            ushort4 h, l;
            h.x = f2bf(pf[i].x); l.x = f2bf(pf[i].x - bf2f(h.x));
            h.y = f2bf(pf[i].y); l.y = f2bf(pf[i].y - bf2f(h.y));
            h.z = f2bf(pf[i].z); l.z = f2bf(pf[i].z - bf2f(h.z));
            h.w = f2bf(pf[i].w); l.w = f2bf(pf[i].w - bf2f(h.w));
            int off = (srow + 16 * i) * LDA + skk;
            *(ushort4*)&As_hi[b][off] = h;
            *(ushort4*)&As_lo[b][off] = l;
        }
    };

    // prologue: load + convert tile 0 into buf 0
    issueA(0);
    convA(0);

    for (int t = 0; t < NT; ++t) {
        __syncthreads();  // buf[t&1] fully written; prior readers of buf[(t+1)&1] done
        const int buf = t & 1;
        // prefetch next tile into registers (latency overlaps compute below)
        if (t + 1 < NT) issueA(t + 1);
        // compute from buf
#pragma unroll
        for (int s = 0; s < 2; ++s) {
            short8 ah[4], al[4];
#pragma unroll
            for (int mi = 0; mi < 4; ++mi) {
                int off = (mi * 16 + m) * LDA + s * 32 + quad * 8;
                ah[mi] = *(const short8*)&As_hi[buf][off];
                al[mi] = *(const short8*)&As_lo[buf][off];
            }
#pragma unroll
            for (int ni = 0; ni < NPW; ++ni) {
                int n = (w * NPW + ni) * 16 + m;
                long boff = (long)n * K + t * 64 + s * 32 + quad * 8;
                short8 bh = *(const short8*)&Bt_hi[boff];
                short8 bl = *(const short8*)&Bt_lo[boff];
#pragma unroll
                for (int mi = 0; mi < 4; ++mi) {
                    acc[mi][ni] = __builtin_amdgcn_mfma_f32_16x16x32_bf16(ah[mi], bh, acc[mi][ni], 0, 0, 0);
                    acc[mi][ni] = __builtin_amdgcn_mfma_f32_16x16x32_bf16(ah[mi], bl, acc[mi][ni], 0, 0, 0);
                    acc[mi][ni] = __builtin_amdgcn_mfma_f32_16x16x32_bf16(al[mi], bh, acc[mi][ni], 0, 0, 0);
                }
            }
        }
        // convert prefetched regs into the other buffer
        if (t + 1 < NT) convA(buf ^ 1);
    }

    // epilogue: C/D layout col=lane&15, row=quad*4+reg; scale by dinv[row]; fp16 store
#pragma unroll
    for (int mi = 0; mi < 4; ++mi) {
#pragma unroll
        for (int r = 0; r < 4; ++r) {
            int row = m0 + mi * 16 + quad * 4 + r;
            if (row < M) {
                float dv = dinv[row];
#pragma unroll
                for (int ni = 0; ni < NPW; ++ni) {
                    int n = (w * NPW + ni) * 16 + m;
                    Hs[(long)row * N + n] = f2h(acc[mi][ni][r] * dv);
                }
            }
        }
    }
}

// ---------------- CSR aggregation: quarter-wave gathers (R6 form) --------------------
// One node per wave. Quarter q processes edges j = rs+q, rs+q+4, ... (16 lanes x 16 B
// = one full 256 B row per gather). 4x unroll main + 2x unroll remainder (mean degree
// 16 -> main loop runs <=1 iter; the serial remainder tail dominates without the 2x).
// Quarters combined via __shfl_xor(16,32). z1 output fp16 (halves write + gemm2 read).
__global__ __launch_bounds__(256) void k_agg1(
    const unsigned short* __restrict__ h, const int* __restrict__ row_ptr,
    const int* __restrict__ col, const float* __restrict__ dinv,
    const float* __restrict__ bias, unsigned short* __restrict__ z, int n) {
    int node = blockIdx.x * 4 + (threadIdx.x >> 6);
    node = __builtin_amdgcn_readfirstlane(node);
    if (node >= n) return;
    int lane = threadIdx.x & 63;
    int q = lane >> 4, li = lane & 15;
    const uint4* hp = (const uint4*)h;  // 16 uint4 per row (128 ch fp16 = 256 B)
    float acc[8] = {0.f, 0.f, 0.f, 0.f, 0.f, 0.f, 0.f, 0.f};
    auto addrow = [&](uint4 v) {
        acc[0] += h2f(v.x); acc[1] += h2f(v.x >> 16);
        acc[2] += h2f(v.y); acc[3] += h2f(v.y >> 16);
        acc[4] += h2f(v.z); acc[5] += h2f(v.z >> 16);
        acc[6] += h2f(v.w); acc[7] += h2f(v.w >> 16);
    };
    if (q == 0) addrow(hp[(long)node * 16 + li]);  // self-loop once
    int rs = row_ptr[node], re = row_ptr[node + 1];
    int j = rs + q;
    for (; j + 12 < re; j += 16) {  // 4 gathers in flight per quarter
        int s0 = col[j], s1 = col[j + 4], s2 = col[j + 8], s3 = col[j + 12];
        uint4 v0 = hp[(long)s0 * 16 + li];
        uint4 v1 = hp[(long)s1 * 16 + li];
        uint4 v2 = hp[(long)s2 * 16 + li];
        uint4 v3 = hp[(long)s3 * 16 + li];
        addrow(v0); addrow(v1); addrow(v2); addrow(v3);
    }
    for (; j + 4 < re; j += 8) {    // 2 in flight
        int s0 = col[j], s1 = col[j + 4];
        uint4 v0 = hp[(long)s0 * 16 + li];
        uint4 v1 = hp[(long)s1 * 16 + li];
        addrow(v0); addrow(v1);
    }
    for (; j < re; j += 4) addrow(hp[(long)col[j] * 16 + li]);
    // combine quarters: lanes {li, li+16, li+32, li+48} hold partials of same channels
#pragma unroll
    for (int k = 0; k < 8; ++k) {
        acc[k] += __shfl_xor(acc[k], 16);
        acc[k] += __shfl_xor(acc[k], 32);
    }
    if (q == 0) {
        float dv = dinv[node];
        const float4* bp = (const float4*)bias;
        float4 b0 = bp[li * 2], b1 = bp[li * 2 + 1];
        uint4 o;
        o.x = packh2(fmaxf(fmaf(acc[0], dv, b0.x), 0.f), fmaxf(fmaf(acc[1], dv, b0.y), 0.f));
        o.y = packh2(fmaxf(fmaf(acc[2], dv, b0.z), 0.f), fmaxf(fmaf(acc[3], dv, b0.w), 0.f));
        o.z = packh2(fmaxf(fmaf(acc[4], dv, b1.x), 0.f), fmaxf(fmaf(acc[5], dv, b1.y), 0.f));
        o.w = packh2(fmaxf(fmaf(acc[6], dv, b1.z), 0.f), fmaxf(fmaf(acc[7], dv, b1.w), 0.f));
        ((uint4*)z)[(long)node * 16 + li] = o;  // z1 fp16, [node][128]
    }
}

__global__ __launch_bounds__(256) void k_agg2(
    const unsigned short* __restrict__ h, const int* __restrict__ row_ptr,
    const int* __restrict__ col, const float* __restrict__ dinv,
    const float* __restrict__ bias, float* __restrict__ z, int n) {
    int node = blockIdx.x * 4 + (threadIdx.x >> 6);
    node = __builtin_amdgcn_readfirstlane(node);
    if (node >= n) return;
    int lane = threadIdx.x & 63;
    int q = lane >> 4, li = lane & 15;
    const uint2* hp = (const uint2*)h;  // 16 uint2 per row (64 ch fp16 = 128 B)
    float acc[4] = {0.f, 0.f, 0.f, 0.f};
    auto addrow = [&](uint2 v) {
        acc[0] += h2f(v.x); acc[1] += h2f(v.x >> 16);
        acc[2] += h2f(v.y); acc[3] += h2f(v.y >> 16);
    };
    if (q == 0) addrow(hp[(long)node * 16 + li]);  // self-loop
    int rs = row_ptr[node], re = row_ptr[node + 1];
    int j = rs + q;
    for (; j + 12 < re; j += 16) {
        int s0 = col[j], s1 = col[j + 4], s2 = col[j + 8], s3 = col[j + 12];
        uint2 v0 = hp[(long)s0 * 16 + li];
        uint2 v1 = hp[(long)s1 * 16 + li];
        uint2 v2 = hp[(long)s2 * 16 + li];
        uint2 v3 = hp[(long)s3 * 16 + li];
        addrow(v0); addrow(v1); addrow(v2); addrow(v3);
    }
    for (; j + 4 < re; j += 8) {
        int s0 = col[j], s1 = col[j + 4];
        uint2 v0 = hp[(long)s0 * 16 + li];
        uint2 v1 = hp[(long)s1 * 16 + li];
        addrow(v0); addrow(v1);
    }
    for (; j < re; j += 4) addrow(hp[(long)col[j] * 16 + li]);
#pragma unroll
    for (int k = 0; k < 4; ++k) {
        acc[k] += __shfl_xor(acc[k], 16);
        acc[k] += __shfl_xor(acc[k], 32);
    }
    if (q == 0) {
        float dv = dinv[node];
        float4 b = ((const float4*)bias)[li];
        float4 o;
        o.x = fmaf(acc[0], dv, b.x);
        o.y = fmaf(acc[1], dv, b.y);
        o.z = fmaf(acc[2], dv, b.z);
        o.w = fmaf(acc[3], dv, b.w);
        ((float4*)z)[(long)node * 16 + li] = o;
    }
}

// ---------------- decoder: 4 edges per wave (quarter-wave each, float4 per lane) ------
__global__ void k_dot(const float* __restrict__ z2, const int* __restrict__ es,
                      const int* __restrict__ ed, float* __restrict__ out, int L) {
    int gid = blockIdx.x * blockDim.x + threadIdx.x;
    int wid = gid >> 6;
    int lane = threadIdx.x & 63;
    int q = lane >> 4, li = lane & 15;
    int e = wid * 4 + q;
    if (e >= L) return;
    int a = es[e], b = ed[e];
    const float4* zp = (const float4*)z2;  // 16 float4 per row (64 ch fp32)
    float4 za = zp[(long)a * 16 + li];
    float4 zb = zp[(long)b * 16 + li];
    float v = za.x * zb.x + za.y * zb.y + za.z * zb.z + za.w * zb.w;
#pragma unroll
    for (int off = 8; off > 0; off >>= 1) v += __shfl_xor(v, off);  // within quarter
    if (li == 0) out[e] = v;
}

extern "C" void kernel_launch(void* const* d_in, const int* in_sizes, int n_in,
                              void* d_out, int out_size, void* d_ws, size_t ws_size,
                              hipStream_t stream) {
    const float* x = (const float*)d_in[0];
    const int* ei = (const int*)d_in[1];
    const int* eli = (const int*)d_in[2];
    const float* W1 = (const float*)d_in[3];
    const float* b1 = (const float*)d_in[4];
    const float* W2 = (const float*)d_in[5];
    const float* b2 = (const float*)d_in[6];
    float* out = (float*)d_out;

    const int N = in_sizes[0] / IN_C;  // 50000
    const int E = in_sizes[1] / 2;     // 800000
    const int L = in_sizes[2] / 2;     // 100000
    const int* src = ei;
    const int* dst = ei + E;
    const int* es = eli;
    const int* ed = eli + L;

    const int Npad = (N + 63) & ~63;
    const int Epad = (E + 3) & ~3;

    // workspace layout
    int* cnt = (int*)d_ws;             // Npad (also the fill cursor, consumed)
    int* row_ptr = cnt + Npad;         // Npad + 64
    int* bsum = row_ptr + Npad + 64;   // 256
    int* col = bsum + 256;             // Epad
    float* dinv = (float*)(col + Epad);                   // Npad
    unsigned short* h1s = (unsigned short*)(dinv + Npad); // N*128 fp16
    unsigned short* z1 = h1s + (long)N * HID_C;           // N*128 fp16
    unsigned short* h2s = h1s;                            // alias: h1s dead after agg1
    float* z2 = (float*)(z1 + (long)N * HID_C);           // N*64 fp32
    unsigned short* wt1_hi = (unsigned short*)(z2 + (long)N * OUT_C);  // 512*128
    unsigned short* wt1_lo = wt1_hi + IN_C * HID_C;
    unsigned short* wt2_hi = wt1_lo + IN_C * HID_C;                    // 128*64
    unsigned short* wt2_lo = wt2_hi + HID_C * OUT_C;

    const int TPB = 256;
    const int nb = (N + 255) / 256;

    // weight prep (both layers, one launch)
    const int PW = IN_C * HID_C + HID_C * OUT_C;
    k_prep_w2<<<(PW + TPB - 1) / TPB, TPB, 0, stream>>>(W1, wt1_hi, wt1_lo, W2, wt2_hi, wt2_lo);

    // CSR build + dinv
    k_zero_int<<<(Npad + TPB - 1) / TPB, TPB, 0, stream>>>(cnt, Npad);
    k_count<<<(E + TPB - 1) / TPB, TPB, 0, stream>>>(dst, cnt, E);
    k_blocksum_dinv<<<nb, 256, 0, stream>>>(cnt, bsum, dinv, N);
    k_scanpartials<<<1, 256, 0, stream>>>(bsum, nb);
    k_scanfinal<<<nb, 256, 0, stream>>>(cnt, bsum, row_ptr, N, E);
    k_fill<<<(E + TPB - 1) / TPB, TPB, 0, stream>>>(src, dst, row_ptr, cnt, col, E);

    // layer 1 (A fp32)
    k_gemm_mfma<IN_C, 2, false><<<(N + 63) / 64, 256, 0, stream>>>(x, wt1_hi, wt1_lo, dinv, h1s, N);
    k_agg1<<<(N + 3) / 4, 256, 0, stream>>>(h1s, row_ptr, col, dinv, b1, z1, N);

    // layer 2 (A = z1 fp16)
    k_gemm_mfma<HID_C, 1, true><<<(N + 63) / 64, 256, 0, stream>>>(z1, wt2_hi, wt2_lo, dinv, h2s, N);
    k_agg2<<<(N + 3) / 4, 256, 0, stream>>>(h2s, row_ptr, col, dinv, b2, z2, N);

    // decoder (4 edges/wave)
    k_dot<<<((long)((L + 3) / 4) * 64 + TPB - 1) / TPB, TPB, 0, stream>>>(z2, es, ed, out, L);
}

// Round 9
// 357.901 us; speedup vs baseline: 1.1908x; 1.0163x over previous
//
#include <hip/hip_runtime.h>

// GCN 2-layer + edge dot decoder. Dims fixed: in=512, hid=128, out=64.
#define IN_C  512
#define HID_C 128
#define OUT_C 64

using short8 = __attribute__((ext_vector_type(8))) short;   // 8 bf16
using floatx4 = __attribute__((ext_vector_type(4))) float;  // mfma acc

__device__ inline unsigned short f2bf(float f) {  // RNE
    unsigned u = __builtin_bit_cast(unsigned, f);
    u += 0x7FFFu + ((u >> 16) & 1u);
    return (unsigned short)(u >> 16);
}
__device__ inline float bf2f(unsigned short h) {
    unsigned u = ((unsigned)h) << 16;
    return __builtin_bit_cast(float, u);
}
__device__ inline unsigned short f2h(float f) {  // fp32 -> fp16 RNE
    _Float16 h = (_Float16)f;
    return __builtin_bit_cast(unsigned short, h);
}
__device__ inline float h2f(unsigned v) {  // low 16 bits = fp16
    return (float)__builtin_bit_cast(_Float16, (unsigned short)v);
}
__device__ inline unsigned packh2(float a, float b) {
    return (unsigned)f2h(a) | ((unsigned)f2h(b) << 16);
}

// ---------------- CSR build ----------------
__global__ void k_zero_int(int* __restrict__ p, int n) {
    int i = blockIdx.x * blockDim.x + threadIdx.x;
    if (i < n) p[i] = 0;
}

__global__ void k_count(const int* __restrict__ dst, int* __restrict__ cnt, int e) {
    int i = blockIdx.x * blockDim.x + threadIdx.x;
    if (i < e) atomicAdd(&cnt[dst[i]], 1);
}

// block-sum of cnt + dinv computed in the same pass (cnt is final here)
__global__ void k_blocksum_dinv(const int* __restrict__ cnt, int* __restrict__ bsum,
                                float* __restrict__ dinv, int n) {
    __shared__ int sdata[256];
    int t = threadIdx.x;
    int i = blockIdx.x * 256 + t;
    int c = (i < n) ? cnt[i] : 0;
    if (i < n) dinv[i] = rsqrtf(1.0f + (float)c);  // +1 self-loop
    sdata[t] = c;
    __syncthreads();
    for (int s = 128; s > 0; s >>= 1) {
        if (t < s) sdata[t] += sdata[t + s];
        __syncthreads();
    }
    if (t == 0) bsum[blockIdx.x] = sdata[0];
}

__global__ void k_scanpartials(int* __restrict__ bsum, int nb) {
    __shared__ int sdata[256];
    int t = threadIdx.x;
    int orig = (t < nb) ? bsum[t] : 0;
    sdata[t] = orig;
    __syncthreads();
    for (int off = 1; off < 256; off <<= 1) {
        int v = (t >= off) ? sdata[t - off] : 0;
        __syncthreads();
        sdata[t] += v;
        __syncthreads();
    }
    if (t < nb) bsum[t] = sdata[t] - orig;  // exclusive
}

__global__ void k_scanfinal(const int* __restrict__ cnt, const int* __restrict__ bsum_ex,
                            int* __restrict__ row_ptr, int n, int e_total) {
    __shared__ int sdata[256];
    int t = threadIdx.x;
    int i = blockIdx.x * 256 + t;
    int orig = (i < n) ? cnt[i] : 0;
    sdata[t] = orig;
    __syncthreads();
    for (int off = 1; off < 256; off <<= 1) {
        int v = (t >= off) ? sdata[t - off] : 0;
        __syncthreads();
        sdata[t] += v;
        __syncthreads();
    }
    if (i < n) row_ptr[i] = sdata[t] - orig + bsum_ex[blockIdx.x];
    if (i == 0) row_ptr[n] = e_total;
}

// destructive fill: consumes cnt as a down-counter (cnt no longer needed after)
__global__ void k_fill(const int* __restrict__ src, const int* __restrict__ dst,
                       const int* __restrict__ row_ptr, int* __restrict__ cnt,
                       int* __restrict__ col, int e) {
    int i = blockIdx.x * blockDim.x + threadIdx.x;
    if (i < e) {
        int d = dst[i];
        int pos = atomicSub(&cnt[d], 1) - 1;  // unique slot in [0, deg)
        col[row_ptr[d] + pos] = src[i];
    }
}

// ---------------- weight prep (both layers in one launch) ----------------
__global__ void k_prep_w2(const float* __restrict__ W1, unsigned short* __restrict__ hi1,
                          unsigned short* __restrict__ lo1, const float* __restrict__ W2,
                          unsigned short* __restrict__ hi2, unsigned short* __restrict__ lo2) {
    int i = blockIdx.x * blockDim.x + threadIdx.x;
    if (i < IN_C * HID_C) {
        int k = i / HID_C, n = i % HID_C;
        float v = W1[i];
        unsigned short h = f2bf(v);
        hi1[(long)n * IN_C + k] = h;
        lo1[(long)n * IN_C + k] = f2bf(v - bf2f(h));
    } else if (i < IN_C * HID_C + HID_C * OUT_C) {
        int j = i - IN_C * HID_C;
        int k = j / OUT_C, n = j % OUT_C;
        float v = W2[j];
        unsigned short h = f2bf(v);
        hi2[(long)n * HID_C + k] = h;
        lo2[(long)n * HID_C + k] = f2bf(v - bf2f(h));
    }
}

// ---------------- gemm1: 8-wave split-bf16 MFMA GEMM (K=512, N=128) -----------------
// Same 64x512 tile, same 782 blocks, same 8 barriers/block as the locked 4-wave form —
// but 512 threads (8 waves, 1 col-set each). Grid is only 3 blocks/CU; 8 waves/block
// raises resident waves 12 -> 24/CU without shrinking the tile (R1's mistake) or
// adding barrier frequency. Per-output k-summation order identical -> bitwise-same.
__global__ __launch_bounds__(512) void k_gemm_mfma8(
    const float* __restrict__ A, const unsigned short* __restrict__ Bt_hi,
    const unsigned short* __restrict__ Bt_lo, const float* __restrict__ dinv,
    unsigned short* __restrict__ Hs, int M) {
    constexpr int K = IN_C;       // 512
    constexpr int N = HID_C;      // 128
    constexpr int LDA = 72;       // shorts; 144 B rows: frag b128 reads land 2-way (free)
    constexpr int NT = K / 64;    // 8 k-tiles
    __shared__ __align__(16) unsigned short As_hi[2][64 * LDA];
    __shared__ __align__(16) unsigned short As_lo[2][64 * LDA];

    const int tid = threadIdx.x;
    const int w = tid >> 6;       // 0..7
    const int lane = tid & 63;
    const int m = lane & 15;
    const int quad = lane >> 4;
    const int m0 = blockIdx.x * 64;

    // staging: thread handles row srow, two float4 at cols skk and skk+32
    const int srow = tid >> 3;          // 0..63
    const int skk = (tid & 7) << 2;     // 0,4,...,28 (8 lanes cover 128 B contiguous)

    floatx4 acc[4];
#pragma unroll
    for (int mi = 0; mi < 4; ++mi) acc[mi] = (floatx4){0.f, 0.f, 0.f, 0.f};

    float4 pf[2];
    auto issueA = [&](int t0) {
        int gm = m0 + srow;
        pf[0] = make_float4(0.f, 0.f, 0.f, 0.f);
        pf[1] = make_float4(0.f, 0.f, 0.f, 0.f);
        if (gm < M) {
            pf[0] = *(const float4*)&A[(long)gm * K + t0 * 64 + skk];
            pf[1] = *(const float4*)&A[(long)gm * K + t0 * 64 + skk + 32];
        }
    };
    auto convA = [&](int b) {
#pragma unroll
        for (int i = 0; i < 2; ++i) {
            ushort4 h, l;
            h.x = f2bf(pf[i].x); l.x = f2bf(pf[i].x - bf2f(h.x));
            h.y = f2bf(pf[i].y); l.y = f2bf(pf[i].y - bf2f(h.y));
            h.z = f2bf(pf[i].z); l.z = f2bf(pf[i].z - bf2f(h.z));
            h.w = f2bf(pf[i].w); l.w = f2bf(pf[i].w - bf2f(h.w));
            int off = srow * LDA + skk + 32 * i;
            *(ushort4*)&As_hi[b][off] = h;
            *(ushort4*)&As_lo[b][off] = l;
        }
    };

    issueA(0);
    convA(0);

    for (int t = 0; t < NT; ++t) {
        __syncthreads();  // buf[t&1] fully written; prior readers of buf[(t+1)&1] done
        const int buf = t & 1;
        if (t + 1 < NT) issueA(t + 1);
#pragma unroll
        for (int s = 0; s < 2; ++s) {
            short8 ah[4], al[4];
#pragma unroll
            for (int mi = 0; mi < 4; ++mi) {
                int off = (mi * 16 + m) * LDA + s * 32 + quad * 8;
                ah[mi] = *(const short8*)&As_hi[buf][off];
                al[mi] = *(const short8*)&As_lo[buf][off];
            }
            int n = w * 16 + m;
            long boff = (long)n * K + t * 64 + s * 32 + quad * 8;
            short8 bh = *(const short8*)&Bt_hi[boff];
            short8 bl = *(const short8*)&Bt_lo[boff];
#pragma unroll
            for (int mi = 0; mi < 4; ++mi) {
                acc[mi] = __builtin_amdgcn_mfma_f32_16x16x32_bf16(ah[mi], bh, acc[mi], 0, 0, 0);
                acc[mi] = __builtin_amdgcn_mfma_f32_16x16x32_bf16(ah[mi], bl, acc[mi], 0, 0, 0);
                acc[mi] = __builtin_amdgcn_mfma_f32_16x16x32_bf16(al[mi], bh, acc[mi], 0, 0, 0);
            }
        }
        if (t + 1 < NT) convA(buf ^ 1);
    }

    // epilogue: C/D layout col=lane&15, row=quad*4+reg; scale by dinv[row]; fp16 store
#pragma unroll
    for (int mi = 0; mi < 4; ++mi) {
#pragma unroll
        for (int r = 0; r < 4; ++r) {
            int row = m0 + mi * 16 + quad * 4 + r;
            if (row < M) {
                int n = w * 16 + m;
                Hs[(long)row * N + n] = f2h(acc[mi][r] * dinv[row]);
            }
        }
    }
}

// ---------------- gemm2: 4-wave split-bf16 MFMA GEMM (R8 form, K=128, N=64) ----------
// AH: A is fp16 (ushort) — fp16 -> split-bf16 is exact (11-bit mantissa fits 8+8).
template <int K, int NPW, bool AH, typename AT>
__global__ __launch_bounds__(256) void k_gemm_mfma(
    const AT* __restrict__ A, const unsigned short* __restrict__ Bt_hi,
    const unsigned short* __restrict__ Bt_lo, const float* __restrict__ dinv,
    unsigned short* __restrict__ Hs, int M) {
    constexpr int N = 64 * NPW;
    constexpr int LDA = 72;
    constexpr int NT = K / 64;
    __shared__ __align__(16) unsigned short As_hi[2][64 * LDA];
    __shared__ __align__(16) unsigned short As_lo[2][64 * LDA];

    const int tid = threadIdx.x;
    const int w = tid >> 6;
    const int lane = tid & 63;
    const int m = lane & 15;
    const int quad = lane >> 4;
    const int m0 = blockIdx.x * 64;

    const int srow = tid >> 4;
    const int skk = (tid & 15) << 2;

    floatx4 acc[4][NPW];
#pragma unroll
    for (int mi = 0; mi < 4; ++mi)
#pragma unroll
        for (int ni = 0; ni < NPW; ++ni) acc[mi][ni] = (floatx4){0.f, 0.f, 0.f, 0.f};

    float4 pf[4];
    auto issueA = [&](int t0) {
#pragma unroll
        for (int i = 0; i < 4; ++i) {
            int gm = m0 + srow + 16 * i;
            pf[i] = make_float4(0.f, 0.f, 0.f, 0.f);
            if (gm < M) {
                if constexpr (AH) {
                    ushort4 r = *(const ushort4*)&A[(long)gm * K + t0 * 64 + skk];
                    pf[i] = make_float4(h2f(r.x), h2f(r.y), h2f(r.z), h2f(r.w));
                } else {
                    pf[i] = *(const float4*)&A[(long)gm * K + t0 * 64 + skk];
                }
            }
        }
    };
    auto convA = [&](int b) {
#pragma unroll
        for (int i = 0; i < 4; ++i) {
            ushort4 h, l;
            h.x = f2bf(pf[i].x); l.x = f2bf(pf[i].x - bf2f(h.x));
            h.y = f2bf(pf[i].y); l.y = f2bf(pf[i].y - bf2f(h.y));
            h.z = f2bf(pf[i].z); l.z = f2bf(pf[i].z - bf2f(h.z));
            h.w = f2bf(pf[i].w); l.w = f2bf(pf[i].w - bf2f(h.w));
            int off = (srow + 16 * i) * LDA + skk;
            *(ushort4*)&As_hi[b][off] = h;
            *(ushort4*)&As_lo[b][off] = l;
        }
    };

    issueA(0);
    convA(0);

    for (int t = 0; t < NT; ++t) {
        __syncthreads();
        const int buf = t & 1;
        if (t + 1 < NT) issueA(t + 1);
#pragma unroll
        for (int s = 0; s < 2; ++s) {
            short8 ah[4], al[4];
#pragma unroll
            for (int mi = 0; mi < 4; ++mi) {
                int off = (mi * 16 + m) * LDA + s * 32 + quad * 8;
                ah[mi] = *(const short8*)&As_hi[buf][off];
                al[mi] = *(const short8*)&As_lo[buf][off];
            }
#pragma unroll
            for (int ni = 0; ni < NPW; ++ni) {
                int n = (w * NPW + ni) * 16 + m;
                long boff = (long)n * K + t * 64 + s * 32 + quad * 8;
                short8 bh = *(const short8*)&Bt_hi[boff];
                short8 bl = *(const short8*)&Bt_lo[boff];
#pragma unroll
                for (int mi = 0; mi < 4; ++mi) {
                    acc[mi][ni] = __builtin_amdgcn_mfma_f32_16x16x32_bf16(ah[mi], bh, acc[mi][ni], 0, 0, 0);
                    acc[mi][ni] = __builtin_amdgcn_mfma_f32_16x16x32_bf16(ah[mi], bl, acc[mi][ni], 0, 0, 0);
                    acc[mi][ni] = __builtin_amdgcn_mfma_f32_16x16x32_bf16(al[mi], bh, acc[mi][ni], 0, 0, 0);
                }
            }
        }
        if (t + 1 < NT) convA(buf ^ 1);
    }

#pragma unroll
    for (int mi = 0; mi < 4; ++mi) {
#pragma unroll
        for (int r = 0; r < 4; ++r) {
            int row = m0 + mi * 16 + quad * 4 + r;
            if (row < M) {
                float dv = dinv[row];
#pragma unroll
                for (int ni = 0; ni < NPW; ++ni) {
                    int n = (w * NPW + ni) * 16 + m;
                    Hs[(long)row * N + n] = f2h(acc[mi][ni][r] * dv);
                }
            }
        }
    }
}

// ---------------- CSR aggregation: quarter-wave gathers (R6 form + 2x remainder) ------
__global__ __launch_bounds__(256) void k_agg1(
    const unsigned short* __restrict__ h, const int* __restrict__ row_ptr,
    const int* __restrict__ col, const float* __restrict__ dinv,
    const float* __restrict__ bias, unsigned short* __restrict__ z, int n) {
    int node = blockIdx.x * 4 + (threadIdx.x >> 6);
    node = __builtin_amdgcn_readfirstlane(node);
    if (node >= n) return;
    int lane = threadIdx.x & 63;
    int q = lane >> 4, li = lane & 15;
    const uint4* hp = (const uint4*)h;  // 16 uint4 per row (128 ch fp16 = 256 B)
    float acc[8] = {0.f, 0.f, 0.f, 0.f, 0.f, 0.f, 0.f, 0.f};
    auto addrow = [&](uint4 v) {
        acc[0] += h2f(v.x); acc[1] += h2f(v.x >> 16);
        acc[2] += h2f(v.y); acc[3] += h2f(v.y >> 16);
        acc[4] += h2f(v.z); acc[5] += h2f(v.z >> 16);
        acc[6] += h2f(v.w); acc[7] += h2f(v.w >> 16);
    };
    if (q == 0) addrow(hp[(long)node * 16 + li]);  // self-loop once
    int rs = row_ptr[node], re = row_ptr[node + 1];
    int j = rs + q;
    for (; j + 12 < re; j += 16) {  // 4 gathers in flight per quarter
        int s0 = col[j], s1 = col[j + 4], s2 = col[j + 8], s3 = col[j + 12];
        uint4 v0 = hp[(long)s0 * 16 + li];
        uint4 v1 = hp[(long)s1 * 16 + li];
        uint4 v2 = hp[(long)s2 * 16 + li];
        uint4 v3 = hp[(long)s3 * 16 + li];
        addrow(v0); addrow(v1); addrow(v2); addrow(v3);
    }
    for (; j + 4 < re; j += 8) {    // 2 in flight
        int s0 = col[j], s1 = col[j + 4];
        uint4 v0 = hp[(long)s0 * 16 + li];
        uint4 v1 = hp[(long)s1 * 16 + li];
        addrow(v0); addrow(v1);
    }
    for (; j < re; j += 4) addrow(hp[(long)col[j] * 16 + li]);
#pragma unroll
    for (int k = 0; k < 8; ++k) {
        acc[k] += __shfl_xor(acc[k], 16);
        acc[k] += __shfl_xor(acc[k], 32);
    }
    if (q == 0) {
        float dv = dinv[node];
        const float4* bp = (const float4*)bias;
        float4 b0 = bp[li * 2], b1 = bp[li * 2 + 1];
        uint4 o;
        o.x = packh2(fmaxf(fmaf(acc[0], dv, b0.x), 0.f), fmaxf(fmaf(acc[1], dv, b0.y), 0.f));
        o.y = packh2(fmaxf(fmaf(acc[2], dv, b0.z), 0.f), fmaxf(fmaf(acc[3], dv, b0.w), 0.f));
        o.z = packh2(fmaxf(fmaf(acc[4], dv, b1.x), 0.f), fmaxf(fmaf(acc[5], dv, b1.y), 0.f));
        o.w = packh2(fmaxf(fmaf(acc[6], dv, b1.z), 0.f), fmaxf(fmaf(acc[7], dv, b1.w), 0.f));
        ((uint4*)z)[(long)node * 16 + li] = o;  // z1 fp16, [node][128]
    }
}

__global__ __launch_bounds__(256) void k_agg2(
    const unsigned short* __restrict__ h, const int* __restrict__ row_ptr,
    const int* __restrict__ col, const float* __restrict__ dinv,
    const float* __restrict__ bias, float* __restrict__ z, int n) {
    int node = blockIdx.x * 4 + (threadIdx.x >> 6);
    node = __builtin_amdgcn_readfirstlane(node);
    if (node >= n) return;
    int lane = threadIdx.x & 63;
    int q = lane >> 4, li = lane & 15;
    const uint2* hp = (const uint2*)h;  // 16 uint2 per row (64 ch fp16 = 128 B)
    float acc[4] = {0.f, 0.f, 0.f, 0.f};
    auto addrow = [&](uint2 v) {
        acc[0] += h2f(v.x); acc[1] += h2f(v.x >> 16);
        acc[2] += h2f(v.y); acc[3] += h2f(v.y >> 16);
    };
    if (q == 0) addrow(hp[(long)node * 16 + li]);  // self-loop
    int rs = row_ptr[node], re = row_ptr[node + 1];
    int j = rs + q;
    for (; j + 12 < re; j += 16) {
        int s0 = col[j], s1 = col[j + 4], s2 = col[j + 8], s3 = col[j + 12];
        uint2 v0 = hp[(long)s0 * 16 + li];
        uint2 v1 = hp[(long)s1 * 16 + li];
        uint2 v2 = hp[(long)s2 * 16 + li];
        uint2 v3 = hp[(long)s3 * 16 + li];
        addrow(v0); addrow(v1); addrow(v2); addrow(v3);
    }
    for (; j + 4 < re; j += 8) {
        int s0 = col[j], s1 = col[j + 4];
        uint2 v0 = hp[(long)s0 * 16 + li];
        uint2 v1 = hp[(long)s1 * 16 + li];
        addrow(v0); addrow(v1);
    }
    for (; j < re; j += 4) addrow(hp[(long)col[j] * 16 + li]);
#pragma unroll
    for (int k = 0; k < 4; ++k) {
        acc[k] += __shfl_xor(acc[k], 16);
        acc[k] += __shfl_xor(acc[k], 32);
    }
    if (q == 0) {
        float dv = dinv[node];
        float4 b = ((const float4*)bias)[li];
        float4 o;
        o.x = fmaf(acc[0], dv, b.x);
        o.y = fmaf(acc[1], dv, b.y);
        o.z = fmaf(acc[2], dv, b.z);
        o.w = fmaf(acc[3], dv, b.w);
        ((float4*)z)[(long)node * 16 + li] = o;
    }
}

// ---------------- decoder: 4 edges per wave (quarter-wave each, float4 per lane) ------
__global__ void k_dot(const float* __restrict__ z2, const int* __restrict__ es,
                      const int* __restrict__ ed, float* __restrict__ out, int L) {
    int gid = blockIdx.x * blockDim.x + threadIdx.x;
    int wid = gid >> 6;
    int lane = threadIdx.x & 63;
    int q = lane >> 4, li = lane & 15;
    int e = wid * 4 + q;
    if (e >= L) return;
    int a = es[e], b = ed[e];
    const float4* zp = (const float4*)z2;  // 16 float4 per row (64 ch fp32)
    float4 za = zp[(long)a * 16 + li];
    float4 zb = zp[(long)b * 16 + li];
    float v = za.x * zb.x + za.y * zb.y + za.z * zb.z + za.w * zb.w;
#pragma unroll
    for (int off = 8; off > 0; off >>= 1) v += __shfl_xor(v, off);  // within quarter
    if (li == 0) out[e] = v;
}

extern "C" void kernel_launch(void* const* d_in, const int* in_sizes, int n_in,
                              void* d_out, int out_size, void* d_ws, size_t ws_size,
                              hipStream_t stream) {
    const float* x = (const float*)d_in[0];
    const int* ei = (const int*)d_in[1];
    const int* eli = (const int*)d_in[2];
    const float* W1 = (const float*)d_in[3];
    const float* b1 = (const float*)d_in[4];
    const float* W2 = (const float*)d_in[5];
    const float* b2 = (const float*)d_in[6];
    float* out = (float*)d_out;

    const int N = in_sizes[0] / IN_C;  // 50000
    const int E = in_sizes[1] / 2;     // 800000
    const int L = in_sizes[2] / 2;     // 100000
    const int* src = ei;
    const int* dst = ei + E;
    const int* es = eli;
    const int* ed = eli + L;

    const int Npad = (N + 63) & ~63;
    const int Epad = (E + 3) & ~3;

    // workspace layout
    int* cnt = (int*)d_ws;             // Npad (also the fill cursor, consumed)
    int* row_ptr = cnt + Npad;         // Npad + 64
    int* bsum = row_ptr + Npad + 64;   // 256
    int* col = bsum + 256;             // Epad
    float* dinv = (float*)(col + Epad);                   // Npad
    unsigned short* h1s = (unsigned short*)(dinv + Npad); // N*128 fp16
    unsigned short* z1 = h1s + (long)N * HID_C;           // N*128 fp16
    unsigned short* h2s = h1s;                            // alias: h1s dead after agg1
    float* z2 = (float*)(z1 + (long)N * HID_C);           // N*64 fp32
    unsigned short* wt1_hi = (unsigned short*)(z2 + (long)N * OUT_C);  // 512*128
    unsigned short* wt1_lo = wt1_hi + IN_C * HID_C;
    unsigned short* wt2_hi = wt1_lo + IN_C * HID_C;                    // 128*64
    unsigned short* wt2_lo = wt2_hi + HID_C * OUT_C;

    const int TPB = 256;
    const int nb = (N + 255) / 256;

    // weight prep (both layers, one launch)
    const int PW = IN_C * HID_C + HID_C * OUT_C;
    k_prep_w2<<<(PW + TPB - 1) / TPB, TPB, 0, stream>>>(W1, wt1_hi, wt1_lo, W2, wt2_hi, wt2_lo);

    // CSR build + dinv
    k_zero_int<<<(Npad + TPB - 1) / TPB, TPB, 0, stream>>>(cnt, Npad);
    k_count<<<(E + TPB - 1) / TPB, TPB, 0, stream>>>(dst, cnt, E);
    k_blocksum_dinv<<<nb, 256, 0, stream>>>(cnt, bsum, dinv, N);
    k_scanpartials<<<1, 256, 0, stream>>>(bsum, nb);
    k_scanfinal<<<nb, 256, 0, stream>>>(cnt, bsum, row_ptr, N, E);
    k_fill<<<(E + TPB - 1) / TPB, TPB, 0, stream>>>(src, dst, row_ptr, cnt, col, E);

    // layer 1 (8-wave GEMM: 782 blocks x 512 threads)
    k_gemm_mfma8<<<(N + 63) / 64, 512, 0, stream>>>(x, wt1_hi, wt1_lo, dinv, h1s, N);
    k_agg1<<<(N + 3) / 4, 256, 0, stream>>>(h1s, row_ptr, col, dinv, b1, z1, N);

    // layer 2 (A = z1 fp16, 4-wave GEMM)
    k_gemm_mfma<HID_C, 1, true><<<(N + 63) / 64, 256, 0, stream>>>(z1, wt2_hi, wt2_lo, dinv, h2s, N);
    k_agg2<<<(N + 3) / 4, 256, 0, stream>>>(h2s, row_ptr, col, dinv, b2, z2, N);

    // decoder (4 edges/wave)
    k_dot<<<((long)((L + 3) / 4) * 64 + TPB - 1) / TPB, TPB, 0, stream>>>(z2, es, ed, out, L);
}

// Round 10
// 354.402 us; speedup vs baseline: 1.2025x; 1.0099x over previous
//
#include <hip/hip_runtime.h>

// GCN 2-layer + edge dot decoder. Dims fixed: in=512, hid=128, out=64.
#define IN_C  512
#define HID_C 128
#define OUT_C 64

using short8 = __attribute__((ext_vector_type(8))) short;   // 8 bf16
using floatx4 = __attribute__((ext_vector_type(4))) float;  // mfma acc

__device__ inline unsigned short f2bf(float f) {  // RNE
    unsigned u = __builtin_bit_cast(unsigned, f);
    u += 0x7FFFu + ((u >> 16) & 1u);
    return (unsigned short)(u >> 16);
}
__device__ inline float bf2f(unsigned short h) {
    unsigned u = ((unsigned)h) << 16;
    return __builtin_bit_cast(float, u);
}
__device__ inline unsigned short f2h(float f) {  // fp32 -> fp16 RNE
    _Float16 h = (_Float16)f;
    return __builtin_bit_cast(unsigned short, h);
}
__device__ inline float h2f(unsigned v) {  // low 16 bits = fp16
    return (float)__builtin_bit_cast(_Float16, (unsigned short)v);
}
__device__ inline unsigned packh2(float a, float b) {
    return (unsigned)f2h(a) | ((unsigned)f2h(b) << 16);
}

// ---------------- fused weight prep + counter zeroing (one launch) ----------------
__global__ void k_prep_zero(const float* __restrict__ W1, unsigned short* __restrict__ hi1,
                            unsigned short* __restrict__ lo1, const float* __restrict__ W2,
                            unsigned short* __restrict__ hi2, unsigned short* __restrict__ lo2,
                            int* __restrict__ cnt, int npad) {
    int i = blockIdx.x * blockDim.x + threadIdx.x;
    if (i < IN_C * HID_C) {
        int k = i / HID_C, n = i % HID_C;
        float v = W1[i];
        unsigned short h = f2bf(v);
        hi1[(long)n * IN_C + k] = h;
        lo1[(long)n * IN_C + k] = f2bf(v - bf2f(h));
    } else if (i < IN_C * HID_C + HID_C * OUT_C) {
        int j = i - IN_C * HID_C;
        int k = j / OUT_C, n = j % OUT_C;
        float v = W2[j];
        unsigned short h = f2bf(v);
        hi2[(long)n * HID_C + k] = h;
        lo2[(long)n * HID_C + k] = f2bf(v - bf2f(h));
    } else {
        int j = i - (IN_C * HID_C + HID_C * OUT_C);
        if (j < npad) cnt[j] = 0;
    }
}

// ---------------- CSR build ----------------
__global__ void k_count(const int* __restrict__ dst, int* __restrict__ cnt, int e) {
    int i = blockIdx.x * blockDim.x + threadIdx.x;
    if (i < e) atomicAdd(&cnt[dst[i]], 1);
}

// block-sum of cnt + dinv computed in the same pass (cnt is final here)
__global__ void k_blocksum_dinv(const int* __restrict__ cnt, int* __restrict__ bsum,
                                float* __restrict__ dinv, int n) {
    __shared__ int sdata[256];
    int t = threadIdx.x;
    int i = blockIdx.x * 256 + t;
    int c = (i < n) ? cnt[i] : 0;
    if (i < n) dinv[i] = rsqrtf(1.0f + (float)c);  // +1 self-loop
    sdata[t] = c;
    __syncthreads();
    for (int s = 128; s > 0; s >>= 1) {
        if (t < s) sdata[t] += sdata[t + s];
        __syncthreads();
    }
    if (t == 0) bsum[blockIdx.x] = sdata[0];
}

__global__ void k_scanpartials(int* __restrict__ bsum, int nb) {
    __shared__ int sdata[256];
    int t = threadIdx.x;
    int orig = (t < nb) ? bsum[t] : 0;
    sdata[t] = orig;
    __syncthreads();
    for (int off = 1; off < 256; off <<= 1) {
        int v = (t >= off) ? sdata[t - off] : 0;
        __syncthreads();
        sdata[t] += v;
        __syncthreads();
    }
    if (t < nb) bsum[t] = sdata[t] - orig;  // exclusive
}

__global__ void k_scanfinal(const int* __restrict__ cnt, const int* __restrict__ bsum_ex,
                            int* __restrict__ row_ptr, int n, int e_total) {
    __shared__ int sdata[256];
    int t = threadIdx.x;
    int i = blockIdx.x * 256 + t;
    int orig = (i < n) ? cnt[i] : 0;
    sdata[t] = orig;
    __syncthreads();
    for (int off = 1; off < 256; off <<= 1) {
        int v = (t >= off) ? sdata[t - off] : 0;
        __syncthreads();
        sdata[t] += v;
        __syncthreads();
    }
    if (i < n) row_ptr[i] = sdata[t] - orig + bsum_ex[blockIdx.x];
    if (i == 0) row_ptr[n] = e_total;
}

// destructive fill: consumes cnt as a down-counter. col stores src*16 (premultiplied
// row stride for the aggs' uint4/uint2 indexing -> shorter gather address chains).
__global__ void k_fill(const int* __restrict__ src, const int* __restrict__ dst,
                       const int* __restrict__ row_ptr, int* __restrict__ cnt,
                       int* __restrict__ col, int e) {
    int i = blockIdx.x * blockDim.x + threadIdx.x;
    if (i < e) {
        int d = dst[i];
        int pos = atomicSub(&cnt[d], 1) - 1;  // unique slot in [0, deg)
        col[row_ptr[d] + pos] = src[i] << 4;
    }
}

// ---------------- gemm1: 8-wave split-bf16 MFMA GEMM (K=512, N=128, A fp32) ---------
// 64x512 tile, 782 blocks, 512 threads (8 waves, 1 col-set each). 24 waves/CU.
// Locked from R9: 63.5 us, occupancy 31%.
__global__ __launch_bounds__(512) void k_gemm_mfma8(
    const float* __restrict__ A, const unsigned short* __restrict__ Bt_hi,
    const unsigned short* __restrict__ Bt_lo, const float* __restrict__ dinv,
    unsigned short* __restrict__ Hs, int M) {
    constexpr int K = IN_C;       // 512
    constexpr int N = HID_C;      // 128
    constexpr int LDA = 72;       // shorts; 144 B rows
    constexpr int NT = K / 64;    // 8 k-tiles
    __shared__ __align__(16) unsigned short As_hi[2][64 * LDA];
    __shared__ __align__(16) unsigned short As_lo[2][64 * LDA];

    const int tid = threadIdx.x;
    const int w = tid >> 6;       // 0..7
    const int lane = tid & 63;
    const int m = lane & 15;
    const int quad = lane >> 4;
    const int m0 = blockIdx.x * 64;

    const int srow = tid >> 3;          // 0..63
    const int skk = (tid & 7) << 2;     // float4 col units

    floatx4 acc[4];
#pragma unroll
    for (int mi = 0; mi < 4; ++mi) acc[mi] = (floatx4){0.f, 0.f, 0.f, 0.f};

    float4 pf[2];
    auto issueA = [&](int t0) {
        int gm = m0 + srow;
        pf[0] = make_float4(0.f, 0.f, 0.f, 0.f);
        pf[1] = make_float4(0.f, 0.f, 0.f, 0.f);
        if (gm < M) {
            pf[0] = *(const float4*)&A[(long)gm * K + t0 * 64 + skk];
            pf[1] = *(const float4*)&A[(long)gm * K + t0 * 64 + skk + 32];
        }
    };
    auto convA = [&](int b) {
#pragma unroll
        for (int i = 0; i < 2; ++i) {
            ushort4 h, l;
            h.x = f2bf(pf[i].x); l.x = f2bf(pf[i].x - bf2f(h.x));
            h.y = f2bf(pf[i].y); l.y = f2bf(pf[i].y - bf2f(h.y));
            h.z = f2bf(pf[i].z); l.z = f2bf(pf[i].z - bf2f(h.z));
            h.w = f2bf(pf[i].w); l.w = f2bf(pf[i].w - bf2f(h.w));
            int off = srow * LDA + skk + 32 * i;
            *(ushort4*)&As_hi[b][off] = h;
            *(ushort4*)&As_lo[b][off] = l;
        }
    };

    issueA(0);
    convA(0);

    for (int t = 0; t < NT; ++t) {
        __syncthreads();
        const int buf = t & 1;
        if (t + 1 < NT) issueA(t + 1);
#pragma unroll
        for (int s = 0; s < 2; ++s) {
            short8 ah[4], al[4];
#pragma unroll
            for (int mi = 0; mi < 4; ++mi) {
                int off = (mi * 16 + m) * LDA + s * 32 + quad * 8;
                ah[mi] = *(const short8*)&As_hi[buf][off];
                al[mi] = *(const short8*)&As_lo[buf][off];
            }
            int n = w * 16 + m;
            long boff = (long)n * K + t * 64 + s * 32 + quad * 8;
            short8 bh = *(const short8*)&Bt_hi[boff];
            short8 bl = *(const short8*)&Bt_lo[boff];
#pragma unroll
            for (int mi = 0; mi < 4; ++mi) {
                acc[mi] = __builtin_amdgcn_mfma_f32_16x16x32_bf16(ah[mi], bh, acc[mi], 0, 0, 0);
                acc[mi] = __builtin_amdgcn_mfma_f32_16x16x32_bf16(ah[mi], bl, acc[mi], 0, 0, 0);
                acc[mi] = __builtin_amdgcn_mfma_f32_16x16x32_bf16(al[mi], bh, acc[mi], 0, 0, 0);
            }
        }
        if (t + 1 < NT) convA(buf ^ 1);
    }

#pragma unroll
    for (int mi = 0; mi < 4; ++mi) {
#pragma unroll
        for (int r = 0; r < 4; ++r) {
            int row = m0 + mi * 16 + quad * 4 + r;
            if (row < M) {
                int n = w * 16 + m;
                Hs[(long)row * N + n] = f2h(acc[mi][r] * dinv[row]);
            }
        }
    }
}

// ---------------- gemm2: 8-wave split-bf16 MFMA GEMM (K=128, N=64, A fp16) ----------
// Same 64-row tile and k-order as the 4-wave form (bitwise-identical output), but 8
// waves as 2(M) x 4(N): wave w -> wm = w>>2 owns row-frags {2wm, 2wm+1}, wn = w&3 owns
// col-set wn. 24 waves/CU (was 12). B loads duplicated across wm pairs (L2-resident).
__global__ __launch_bounds__(512) void k_gemm_mfma8_l2(
    const unsigned short* __restrict__ A, const unsigned short* __restrict__ Bt_hi,
    const unsigned short* __restrict__ Bt_lo, const float* __restrict__ dinv,
    unsigned short* __restrict__ Hs, int M) {
    constexpr int K = HID_C;      // 128
    constexpr int N = OUT_C;      // 64
    constexpr int LDA = 72;
    constexpr int NT = K / 64;    // 2 k-tiles
    __shared__ __align__(16) unsigned short As_hi[2][64 * LDA];
    __shared__ __align__(16) unsigned short As_lo[2][64 * LDA];

    const int tid = threadIdx.x;
    const int w = tid >> 6;
    const int wm = w >> 2;        // 0/1: row half
    const int wn = w & 3;         // col-set
    const int lane = tid & 63;
    const int m = lane & 15;
    const int quad = lane >> 4;
    const int m0 = blockIdx.x * 64;

    const int srow = tid >> 3;          // 0..63
    const int skk = (tid & 7) << 2;     // ushort4 col units (shorts 0..28)

    floatx4 acc[2];
    acc[0] = (floatx4){0.f, 0.f, 0.f, 0.f};
    acc[1] = (floatx4){0.f, 0.f, 0.f, 0.f};

    float4 pf[2];
    auto issueA = [&](int t0) {
        int gm = m0 + srow;
        pf[0] = make_float4(0.f, 0.f, 0.f, 0.f);
        pf[1] = make_float4(0.f, 0.f, 0.f, 0.f);
        if (gm < M) {
            ushort4 r0 = *(const ushort4*)&A[(long)gm * K + t0 * 64 + skk];
            ushort4 r1 = *(const ushort4*)&A[(long)gm * K + t0 * 64 + skk + 32];
            pf[0] = make_float4(h2f(r0.x), h2f(r0.y), h2f(r0.z), h2f(r0.w));
            pf[1] = make_float4(h2f(r1.x), h2f(r1.y), h2f(r1.z), h2f(r1.w));
        }
    };
    auto convA = [&](int b) {
#pragma unroll
        for (int i = 0; i < 2; ++i) {
            ushort4 h, l;
            h.x = f2bf(pf[i].x); l.x = f2bf(pf[i].x - bf2f(h.x));
            h.y = f2bf(pf[i].y); l.y = f2bf(pf[i].y - bf2f(h.y));
            h.z = f2bf(pf[i].z); l.z = f2bf(pf[i].z - bf2f(h.z));
            h.w = f2bf(pf[i].w); l.w = f2bf(pf[i].w - bf2f(h.w));
            int off = srow * LDA + skk + 32 * i;
            *(ushort4*)&As_hi[b][off] = h;
            *(ushort4*)&As_lo[b][off] = l;
        }
    };

    issueA(0);
    convA(0);

    for (int t = 0; t < NT; ++t) {
        __syncthreads();
        const int buf = t & 1;
        if (t + 1 < NT) issueA(t + 1);
#pragma unroll
        for (int s = 0; s < 2; ++s) {
            short8 ah[2], al[2];
#pragma unroll
            for (int mi = 0; mi < 2; ++mi) {
                int off = ((wm * 2 + mi) * 16 + m) * LDA + s * 32 + quad * 8;
                ah[mi] = *(const short8*)&As_hi[buf][off];
                al[mi] = *(const short8*)&As_lo[buf][off];
            }
            int n = wn * 16 + m;
            long boff = (long)n * K + t * 64 + s * 32 + quad * 8;
            short8 bh = *(const short8*)&Bt_hi[boff];
            short8 bl = *(const short8*)&Bt_lo[boff];
#pragma unroll
            for (int mi = 0; mi < 2; ++mi) {
                acc[mi] = __builtin_amdgcn_mfma_f32_16x16x32_bf16(ah[mi], bh, acc[mi], 0, 0, 0);
                acc[mi] = __builtin_amdgcn_mfma_f32_16x16x32_bf16(ah[mi], bl, acc[mi], 0, 0, 0);
                acc[mi] = __builtin_amdgcn_mfma_f32_16x16x32_bf16(al[mi], bh, acc[mi], 0, 0, 0);
            }
        }
        if (t + 1 < NT) convA(buf ^ 1);
    }

#pragma unroll
    for (int mi = 0; mi < 2; ++mi) {
#pragma unroll
        for (int r = 0; r < 4; ++r) {
            int row = m0 + (wm * 2 + mi) * 16 + quad * 4 + r;
            if (row < M) {
                int n = wn * 16 + m;
                Hs[(long)row * N + n] = f2h(acc[mi][r] * dinv[row]);
            }
        }
    }
}

// ---------------- CSR aggregation: quarter-wave gathers (col premultiplied x16) ------
__global__ __launch_bounds__(256) void k_agg1(
    const unsigned short* __restrict__ h, const int* __restrict__ row_ptr,
    const int* __restrict__ col, const float* __restrict__ dinv,
    const float* __restrict__ bias, unsigned short* __restrict__ z, int n) {
    int node = blockIdx.x * 4 + (threadIdx.x >> 6);
    node = __builtin_amdgcn_readfirstlane(node);
    if (node >= n) return;
    int lane = threadIdx.x & 63;
    int q = lane >> 4, li = lane & 15;
    const uint4* hp = (const uint4*)h;  // 16 uint4 per row (128 ch fp16 = 256 B)
    float acc[8] = {0.f, 0.f, 0.f, 0.f, 0.f, 0.f, 0.f, 0.f};
    auto addrow = [&](uint4 v) {
        acc[0] += h2f(v.x); acc[1] += h2f(v.x >> 16);
        acc[2] += h2f(v.y); acc[3] += h2f(v.y >> 16);
        acc[4] += h2f(v.z); acc[5] += h2f(v.z >> 16);
        acc[6] += h2f(v.w); acc[7] += h2f(v.w >> 16);
    };
    if (q == 0) addrow(hp[(long)node * 16 + li]);  // self-loop once
    int rs = row_ptr[node], re = row_ptr[node + 1];
    int j = rs + q;
    for (; j + 12 < re; j += 16) {  // 4 gathers in flight per quarter
        int s0 = col[j], s1 = col[j + 4], s2 = col[j + 8], s3 = col[j + 12];
        uint4 v0 = hp[(long)s0 + li];
        uint4 v1 = hp[(long)s1 + li];
        uint4 v2 = hp[(long)s2 + li];
        uint4 v3 = hp[(long)s3 + li];
        addrow(v0); addrow(v1); addrow(v2); addrow(v3);
    }
    for (; j + 4 < re; j += 8) {    // 2 in flight
        int s0 = col[j], s1 = col[j + 4];
        uint4 v0 = hp[(long)s0 + li];
        uint4 v1 = hp[(long)s1 + li];
        addrow(v0); addrow(v1);
    }
    for (; j < re; j += 4) addrow(hp[(long)col[j] + li]);
#pragma unroll
    for (int k = 0; k < 8; ++k) {
        acc[k] += __shfl_xor(acc[k], 16);
        acc[k] += __shfl_xor(acc[k], 32);
    }
    if (q == 0) {
        float dv = dinv[node];
        const float4* bp = (const float4*)bias;
        float4 b0 = bp[li * 2], b1 = bp[li * 2 + 1];
        uint4 o;
        o.x = packh2(fmaxf(fmaf(acc[0], dv, b0.x), 0.f), fmaxf(fmaf(acc[1], dv, b0.y), 0.f));
        o.y = packh2(fmaxf(fmaf(acc[2], dv, b0.z), 0.f), fmaxf(fmaf(acc[3], dv, b0.w), 0.f));
        o.z = packh2(fmaxf(fmaf(acc[4], dv, b1.x), 0.f), fmaxf(fmaf(acc[5], dv, b1.y), 0.f));
        o.w = packh2(fmaxf(fmaf(acc[6], dv, b1.z), 0.f), fmaxf(fmaf(acc[7], dv, b1.w), 0.f));
        ((uint4*)z)[(long)node * 16 + li] = o;  // z1 fp16, [node][128]
    }
}

__global__ __launch_bounds__(256) void k_agg2(
    const unsigned short* __restrict__ h, const int* __restrict__ row_ptr,
    const int* __restrict__ col, const float* __restrict__ dinv,
    const float* __restrict__ bias, float* __restrict__ z, int n) {
    int node = blockIdx.x * 4 + (threadIdx.x >> 6);
    node = __builtin_amdgcn_readfirstlane(node);
    if (node >= n) return;
    int lane = threadIdx.x & 63;
    int q = lane >> 4, li = lane & 15;
    const uint2* hp = (const uint2*)h;  // 16 uint2 per row (64 ch fp16 = 128 B)
    float acc[4] = {0.f, 0.f, 0.f, 0.f};
    auto addrow = [&](uint2 v) {
        acc[0] += h2f(v.x); acc[1] += h2f(v.x >> 16);
        acc[2] += h2f(v.y); acc[3] += h2f(v.y >> 16);
    };
    if (q == 0) addrow(hp[(long)node * 16 + li]);  // self-loop
    int rs = row_ptr[node], re = row_ptr[node + 1];
    int j = rs + q;
    for (; j + 12 < re; j += 16) {
        int s0 = col[j], s1 = col[j + 4], s2 = col[j + 8], s3 = col[j + 12];
        uint2 v0 = hp[(long)s0 + li];
        uint2 v1 = hp[(long)s1 + li];
        uint2 v2 = hp[(long)s2 + li];
        uint2 v3 = hp[(long)s3 + li];
        addrow(v0); addrow(v1); addrow(v2); addrow(v3);
    }
    for (; j + 4 < re; j += 8) {
        int s0 = col[j], s1 = col[j + 4];
        uint2 v0 = hp[(long)s0 + li];
        uint2 v1 = hp[(long)s1 + li];
        addrow(v0); addrow(v1);
    }
    for (; j < re; j += 4) addrow(hp[(long)col[j] + li]);
#pragma unroll
    for (int k = 0; k < 4; ++k) {
        acc[k] += __shfl_xor(acc[k], 16);
        acc[k] += __shfl_xor(acc[k], 32);
    }
    if (q == 0) {
        float dv = dinv[node];
        float4 b = ((const float4*)bias)[li];
        float4 o;
        o.x = fmaf(acc[0], dv, b.x);
        o.y = fmaf(acc[1], dv, b.y);
        o.z = fmaf(acc[2], dv, b.z);
        o.w = fmaf(acc[3], dv, b.w);
        ((float4*)z)[(long)node * 16 + li] = o;
    }
}

// ---------------- decoder: 4 edges per wave (quarter-wave each, float4 per lane) ------
__global__ void k_dot(const float* __restrict__ z2, const int* __restrict__ es,
                      const int* __restrict__ ed, float* __restrict__ out, int L) {
    int gid = blockIdx.x * blockDim.x + threadIdx.x;
    int wid = gid >> 6;
    int lane = threadIdx.x & 63;
    int q = lane >> 4, li = lane & 15;
    int e = wid * 4 + q;
    if (e >= L) return;
    int a = es[e], b = ed[e];
    const float4* zp = (const float4*)z2;  // 16 float4 per row (64 ch fp32)
    float4 za = zp[(long)a * 16 + li];
    float4 zb = zp[(long)b * 16 + li];
    float v = za.x * zb.x + za.y * zb.y + za.z * zb.z + za.w * zb.w;
#pragma unroll
    for (int off = 8; off > 0; off >>= 1) v += __shfl_xor(v, off);  // within quarter
    if (li == 0) out[e] = v;
}

extern "C" void kernel_launch(void* const* d_in, const int* in_sizes, int n_in,
                              void* d_out, int out_size, void* d_ws, size_t ws_size,
                              hipStream_t stream) {
    const float* x = (const float*)d_in[0];
    const int* ei = (const int*)d_in[1];
    const int* eli = (const int*)d_in[2];
    const float* W1 = (const float*)d_in[3];
    const float* b1 = (const float*)d_in[4];
    const float* W2 = (const float*)d_in[5];
    const float* b2 = (const float*)d_in[6];
    float* out = (float*)d_out;

    const int N = in_sizes[0] / IN_C;  // 50000
    const int E = in_sizes[1] / 2;     // 800000
    const int L = in_sizes[2] / 2;     // 100000
    const int* src = ei;
    const int* dst = ei + E;
    const int* es = eli;
    const int* ed = eli + L;

    const int Npad = (N + 63) & ~63;
    const int Epad = (E + 3) & ~3;

    // workspace layout
    int* cnt = (int*)d_ws;             // Npad (also the fill cursor, consumed)
    int* row_ptr = cnt + Npad;         // Npad + 64
    int* bsum = row_ptr + Npad + 64;   // 256
    int* col = bsum + 256;             // Epad
    float* dinv = (float*)(col + Epad);                   // Npad
    unsigned short* h1s = (unsigned short*)(dinv + Npad); // N*128 fp16
    unsigned short* z1 = h1s + (long)N * HID_C;           // N*128 fp16
    unsigned short* h2s = h1s;                            // alias: h1s dead after agg1
    float* z2 = (float*)(z1 + (long)N * HID_C);           // N*64 fp32
    unsigned short* wt1_hi = (unsigned short*)(z2 + (long)N * OUT_C);  // 512*128
    unsigned short* wt1_lo = wt1_hi + IN_C * HID_C;
    unsigned short* wt2_hi = wt1_lo + IN_C * HID_C;                    // 128*64
    unsigned short* wt2_lo = wt2_hi + HID_C * OUT_C;

    const int TPB = 256;
    const int nb = (N + 255) / 256;

    // fused weight prep + cnt zeroing (one launch)
    const int PW = IN_C * HID_C + HID_C * OUT_C + Npad;
    k_prep_zero<<<(PW + TPB - 1) / TPB, TPB, 0, stream>>>(W1, wt1_hi, wt1_lo, W2, wt2_hi, wt2_lo, cnt, Npad);

    // CSR build + dinv
    k_count<<<(E + TPB - 1) / TPB, TPB, 0, stream>>>(dst, cnt, E);
    k_blocksum_dinv<<<nb, 256, 0, stream>>>(cnt, bsum, dinv, N);
    k_scanpartials<<<1, 256, 0, stream>>>(bsum, nb);
    k_scanfinal<<<nb, 256, 0, stream>>>(cnt, bsum, row_ptr, N, E);
    k_fill<<<(E + TPB - 1) / TPB, TPB, 0, stream>>>(src, dst, row_ptr, cnt, col, E);

    // layer 1 (8-wave GEMM: 782 blocks x 512 threads)
    k_gemm_mfma8<<<(N + 63) / 64, 512, 0, stream>>>(x, wt1_hi, wt1_lo, dinv, h1s, N);
    k_agg1<<<(N + 3) / 4, 256, 0, stream>>>(h1s, row_ptr, col, dinv, b1, z1, N);

    // layer 2 (8-wave GEMM, A = z1 fp16)
    k_gemm_mfma8_l2<<<(N + 63) / 64, 512, 0, stream>>>(z1, wt2_hi, wt2_lo, dinv, h2s, N);
    k_agg2<<<(N + 3) / 4, 256, 0, stream>>>(h2s, row_ptr, col, dinv, b2, z2, N);

    // decoder (4 edges/wave)
    k_dot<<<((long)((L + 3) / 4) * 64 + TPB - 1) / TPB, TPB, 0, stream>>>(z2, es, ed, out, L);
}

// Round 11
// 349.094 us; speedup vs baseline: 1.2208x; 1.0152x over previous
//
#include <hip/hip_runtime.h>

// GCN 2-layer + edge dot decoder. Dims fixed: in=512, hid=128, out=64.
#define IN_C  512
#define HID_C 128
#define OUT_C 64

using short8 = __attribute__((ext_vector_type(8))) short;   // 8 bf16 / fp16
using floatx4 = __attribute__((ext_vector_type(4))) float;  // mfma acc

__device__ inline unsigned short f2bf(float f) {  // RNE
    unsigned u = __builtin_bit_cast(unsigned, f);
    u += 0x7FFFu + ((u >> 16) & 1u);
    return (unsigned short)(u >> 16);
}
__device__ inline float bf2f(unsigned short h) {
    unsigned u = ((unsigned)h) << 16;
    return __builtin_bit_cast(float, u);
}
__device__ inline unsigned short f2h(float f) {  // fp32 -> fp16 RNE
    _Float16 h = (_Float16)f;
    return __builtin_bit_cast(unsigned short, h);
}
__device__ inline float h2f(unsigned v) {  // low 16 bits = fp16
    return (float)__builtin_bit_cast(_Float16, (unsigned short)v);
}
__device__ inline unsigned packh2(float a, float b) {
    return (unsigned)f2h(a) | ((unsigned)f2h(b) << 16);
}

// ---------------- fused weight prep + counter zeroing (one launch) ----------------
__global__ void k_prep_zero(const float* __restrict__ W1, unsigned short* __restrict__ hi1,
                            unsigned short* __restrict__ lo1, const float* __restrict__ W2,
                            unsigned short* __restrict__ hi2, unsigned short* __restrict__ lo2,
                            int* __restrict__ cnt, int npad) {
    int i = blockIdx.x * blockDim.x + threadIdx.x;
    if (i < IN_C * HID_C) {
        int k = i / HID_C, n = i % HID_C;
        float v = W1[i];
        unsigned short h = f2bf(v);
        hi1[(long)n * IN_C + k] = h;
        lo1[(long)n * IN_C + k] = f2bf(v - bf2f(h));
    } else if (i < IN_C * HID_C + HID_C * OUT_C) {
        int j = i - IN_C * HID_C;
        int k = j / OUT_C, n = j % OUT_C;
        float v = W2[j];
        unsigned short h = f2bf(v);
        hi2[(long)n * HID_C + k] = h;
        lo2[(long)n * HID_C + k] = f2bf(v - bf2f(h));
    } else {
        int j = i - (IN_C * HID_C + HID_C * OUT_C);
        if (j < npad) cnt[j] = 0;
    }
}

// ---------------- CSR build ----------------
__global__ void k_count(const int* __restrict__ dst, int* __restrict__ cnt, int e) {
    int i = blockIdx.x * blockDim.x + threadIdx.x;
    if (i < e) atomicAdd(&cnt[dst[i]], 1);
}

// block-sum of cnt + dinv computed in the same pass (cnt is final here)
__global__ void k_blocksum_dinv(const int* __restrict__ cnt, int* __restrict__ bsum,
                                float* __restrict__ dinv, int n) {
    __shared__ int sdata[256];
    int t = threadIdx.x;
    int i = blockIdx.x * 256 + t;
    int c = (i < n) ? cnt[i] : 0;
    if (i < n) dinv[i] = rsqrtf(1.0f + (float)c);  // +1 self-loop
    sdata[t] = c;
    __syncthreads();
    for (int s = 128; s > 0; s >>= 1) {
        if (t < s) sdata[t] += sdata[t + s];
        __syncthreads();
    }
    if (t == 0) bsum[blockIdx.x] = sdata[0];
}

__global__ void k_scanpartials(int* __restrict__ bsum, int nb) {
    __shared__ int sdata[256];
    int t = threadIdx.x;
    int orig = (t < nb) ? bsum[t] : 0;
    sdata[t] = orig;
    __syncthreads();
    for (int off = 1; off < 256; off <<= 1) {
        int v = (t >= off) ? sdata[t - off] : 0;
        __syncthreads();
        sdata[t] += v;
        __syncthreads();
    }
    if (t < nb) bsum[t] = sdata[t] - orig;  // exclusive
}

__global__ void k_scanfinal(const int* __restrict__ cnt, const int* __restrict__ bsum_ex,
                            int* __restrict__ row_ptr, int n, int e_total) {
    __shared__ int sdata[256];
    int t = threadIdx.x;
    int i = blockIdx.x * 256 + t;
    int orig = (i < n) ? cnt[i] : 0;
    sdata[t] = orig;
    __syncthreads();
    for (int off = 1; off < 256; off <<= 1) {
        int v = (t >= off) ? sdata[t - off] : 0;
        __syncthreads();
        sdata[t] += v;
        __syncthreads();
    }
    if (i < n) row_ptr[i] = sdata[t] - orig + bsum_ex[blockIdx.x];
    if (i == 0) row_ptr[n] = e_total;
}

// destructive fill: consumes cnt as a down-counter. col stores src*16 (premultiplied
// row stride for the aggs' uint4/uint2 indexing -> shorter gather address chains).
__global__ void k_fill(const int* __restrict__ src, const int* __restrict__ dst,
                       const int* __restrict__ row_ptr, int* __restrict__ cnt,
                       int* __restrict__ col, int e) {
    int i = blockIdx.x * blockDim.x + threadIdx.x;
    if (i < e) {
        int d = dst[i];
        int pos = atomicSub(&cnt[d], 1) - 1;  // unique slot in [0, deg)
        col[row_ptr[d] + pos] = src[i] << 4;
    }
}

// ---------------- gemm1: 8-wave split-bf16 MFMA GEMM (K=512, N=128, A fp32) ---------
// 64x512 tile, 782 blocks, 512 threads. LDS: LDA=64 (no pad) + 16B-unit XOR swizzle
// `o ^= (row&7)<<3` (shorts) on both write and read:
//   writes: bank = 4*((tid&7)^(tid>>3)) -> 8 lanes per 4-bank group = conflict-free
//   reads:  bank = 4*((s*4+quad)^(m&7)) -> 2 lanes/bank = free (m136)
// (was LDA=72: 4-way write conflicts, SQ_LDS_BANK_CONFLICT 4.0M cyc). Same k-order ->
// bitwise-identical output. Each thread stages one contiguous 32B global read.
__global__ __launch_bounds__(512) void k_gemm_mfma8(
    const float* __restrict__ A, const unsigned short* __restrict__ Bt_hi,
    const unsigned short* __restrict__ Bt_lo, const float* __restrict__ dinv,
    unsigned short* __restrict__ Hs, int M) {
    constexpr int K = IN_C;       // 512
    constexpr int N = HID_C;      // 128
    constexpr int LDA = 64;       // shorts; swizzled, no pad
    constexpr int NT = K / 64;    // 8 k-tiles
    __shared__ __align__(16) unsigned short As_hi[2][64 * LDA];
    __shared__ __align__(16) unsigned short As_lo[2][64 * LDA];

    const int tid = threadIdx.x;
    const int w = tid >> 6;       // 0..7
    const int lane = tid & 63;
    const int m = lane & 15;
    const int quad = lane >> 4;
    const int m0 = blockIdx.x * 64;

    const int srow = tid >> 3;          // 0..63
    const int scol = (tid & 7) << 3;    // shorts/halved-floats: 8-elem chunk
    const int swoff = srow * LDA + (scol ^ ((srow & 7) << 3));  // swizzled write offset

    floatx4 acc[4];
#pragma unroll
    for (int mi = 0; mi < 4; ++mi) acc[mi] = (floatx4){0.f, 0.f, 0.f, 0.f};

    float4 pf[2];
    auto issueA = [&](int t0) {
        int gm = m0 + srow;
        pf[0] = make_float4(0.f, 0.f, 0.f, 0.f);
        pf[1] = make_float4(0.f, 0.f, 0.f, 0.f);
        if (gm < M) {
            pf[0] = *(const float4*)&A[(long)gm * K + t0 * 64 + scol];
            pf[1] = *(const float4*)&A[(long)gm * K + t0 * 64 + scol + 4];
        }
    };
    auto convA = [&](int b) {
        short8 h, l;
#pragma unroll
        for (int i = 0; i < 2; ++i) {
            unsigned short hx, hy, hz, hw;
            hx = f2bf(pf[i].x); hy = f2bf(pf[i].y); hz = f2bf(pf[i].z); hw = f2bf(pf[i].w);
            h[i * 4 + 0] = (short)hx; l[i * 4 + 0] = (short)f2bf(pf[i].x - bf2f(hx));
            h[i * 4 + 1] = (short)hy; l[i * 4 + 1] = (short)f2bf(pf[i].y - bf2f(hy));
            h[i * 4 + 2] = (short)hz; l[i * 4 + 2] = (short)f2bf(pf[i].z - bf2f(hz));
            h[i * 4 + 3] = (short)hw; l[i * 4 + 3] = (short)f2bf(pf[i].w - bf2f(hw));
        }
        *(short8*)&As_hi[b][swoff] = h;
        *(short8*)&As_lo[b][swoff] = l;
    };

    issueA(0);
    convA(0);

    for (int t = 0; t < NT; ++t) {
        __syncthreads();
        const int buf = t & 1;
        if (t + 1 < NT) issueA(t + 1);
#pragma unroll
        for (int s = 0; s < 2; ++s) {
            short8 ah[4], al[4];
#pragma unroll
            for (int mi = 0; mi < 4; ++mi) {
                int row = mi * 16 + m;
                int off = row * LDA + ((s * 32 + quad * 8) ^ ((m & 7) << 3));
                ah[mi] = *(const short8*)&As_hi[buf][off];
                al[mi] = *(const short8*)&As_lo[buf][off];
            }
            int n = w * 16 + m;
            long boff = (long)n * K + t * 64 + s * 32 + quad * 8;
            short8 bh = *(const short8*)&Bt_hi[boff];
            short8 bl = *(const short8*)&Bt_lo[boff];
#pragma unroll
            for (int mi = 0; mi < 4; ++mi) {
                acc[mi] = __builtin_amdgcn_mfma_f32_16x16x32_bf16(ah[mi], bh, acc[mi], 0, 0, 0);
                acc[mi] = __builtin_amdgcn_mfma_f32_16x16x32_bf16(ah[mi], bl, acc[mi], 0, 0, 0);
                acc[mi] = __builtin_amdgcn_mfma_f32_16x16x32_bf16(al[mi], bh, acc[mi], 0, 0, 0);
            }
        }
        if (t + 1 < NT) convA(buf ^ 1);
    }

#pragma unroll
    for (int mi = 0; mi < 4; ++mi) {
#pragma unroll
        for (int r = 0; r < 4; ++r) {
            int row = m0 + mi * 16 + quad * 4 + r;
            if (row < M) {
                int n = w * 16 + m;
                Hs[(long)row * N + n] = f2h(acc[mi][r] * dinv[row]);
            }
        }
    }
}

// ---------------- gemm2: 8-wave split-bf16 MFMA GEMM (K=128, N=64, A fp16) ----------
// Waves 2(M) x 4(N). Same swizzled LDA=64 staging as gemm1. Bitwise-identical k-order.
__global__ __launch_bounds__(512) void k_gemm_mfma8_l2(
    const unsigned short* __restrict__ A, const unsigned short* __restrict__ Bt_hi,
    const unsigned short* __restrict__ Bt_lo, const float* __restrict__ dinv,
    unsigned short* __restrict__ Hs, int M) {
    constexpr int K = HID_C;      // 128
    constexpr int N = OUT_C;      // 64
    constexpr int LDA = 64;
    constexpr int NT = K / 64;    // 2 k-tiles
    __shared__ __align__(16) unsigned short As_hi[2][64 * LDA];
    __shared__ __align__(16) unsigned short As_lo[2][64 * LDA];

    const int tid = threadIdx.x;
    const int w = tid >> 6;
    const int wm = w >> 2;        // 0/1: row half
    const int wn = w & 3;         // col-set
    const int lane = tid & 63;
    const int m = lane & 15;
    const int quad = lane >> 4;
    const int m0 = blockIdx.x * 64;

    const int srow = tid >> 3;          // 0..63
    const int scol = (tid & 7) << 3;    // 8-half chunk
    const int swoff = srow * LDA + (scol ^ ((srow & 7) << 3));

    floatx4 acc[2];
    acc[0] = (floatx4){0.f, 0.f, 0.f, 0.f};
    acc[1] = (floatx4){0.f, 0.f, 0.f, 0.f};

    float4 pf[2];
    auto issueA = [&](int t0) {
        int gm = m0 + srow;
        pf[0] = make_float4(0.f, 0.f, 0.f, 0.f);
        pf[1] = make_float4(0.f, 0.f, 0.f, 0.f);
        if (gm < M) {
            ushort4 r0 = *(const ushort4*)&A[(long)gm * K + t0 * 64 + scol];
            ushort4 r1 = *(const ushort4*)&A[(long)gm * K + t0 * 64 + scol + 4];
            pf[0] = make_float4(h2f(r0.x), h2f(r0.y), h2f(r0.z), h2f(r0.w));
            pf[1] = make_float4(h2f(r1.x), h2f(r1.y), h2f(r1.z), h2f(r1.w));
        }
    };
    auto convA = [&](int b) {
        short8 h, l;
#pragma unroll
        for (int i = 0; i < 2; ++i) {
            unsigned short hx, hy, hz, hw;
            hx = f2bf(pf[i].x); hy = f2bf(pf[i].y); hz = f2bf(pf[i].z); hw = f2bf(pf[i].w);
            h[i * 4 + 0] = (short)hx; l[i * 4 + 0] = (short)f2bf(pf[i].x - bf2f(hx));
            h[i * 4 + 1] = (short)hy; l[i * 4 + 1] = (short)f2bf(pf[i].y - bf2f(hy));
            h[i * 4 + 2] = (short)hz; l[i * 4 + 2] = (short)f2bf(pf[i].z - bf2f(hz));
            h[i * 4 + 3] = (short)hw; l[i * 4 + 3] = (short)f2bf(pf[i].w - bf2f(hw));
        }
        *(short8*)&As_hi[b][swoff] = h;
        *(short8*)&As_lo[b][swoff] = l;
    };

    issueA(0);
    convA(0);

    for (int t = 0; t < NT; ++t) {
        __syncthreads();
        const int buf = t & 1;
        if (t + 1 < NT) issueA(t + 1);
#pragma unroll
        for (int s = 0; s < 2; ++s) {
            short8 ah[2], al[2];
#pragma unroll
            for (int mi = 0; mi < 2; ++mi) {
                int row = (wm * 2 + mi) * 16 + m;
                int off = row * LDA + ((s * 32 + quad * 8) ^ ((m & 7) << 3));
                ah[mi] = *(const short8*)&As_hi[buf][off];
                al[mi] = *(const short8*)&As_lo[buf][off];
            }
            int n = wn * 16 + m;
            long boff = (long)n * K + t * 64 + s * 32 + quad * 8;
            short8 bh = *(const short8*)&Bt_hi[boff];
            short8 bl = *(const short8*)&Bt_lo[boff];
#pragma unroll
            for (int mi = 0; mi < 2; ++mi) {
                acc[mi] = __builtin_amdgcn_mfma_f32_16x16x32_bf16(ah[mi], bh, acc[mi], 0, 0, 0);
                acc[mi] = __builtin_amdgcn_mfma_f32_16x16x32_bf16(ah[mi], bl, acc[mi], 0, 0, 0);
                acc[mi] = __builtin_amdgcn_mfma_f32_16x16x32_bf16(al[mi], bh, acc[mi], 0, 0, 0);
            }
        }
        if (t + 1 < NT) convA(buf ^ 1);
    }

#pragma unroll
    for (int mi = 0; mi < 2; ++mi) {
#pragma unroll
        for (int r = 0; r < 4; ++r) {
            int row = m0 + (wm * 2 + mi) * 16 + quad * 4 + r;
            if (row < M) {
                int n = wn * 16 + m;
                Hs[(long)row * N + n] = f2h(acc[mi][r] * dinv[row]);
            }
        }
    }
}

// ---------------- CSR aggregation: quarter-wave gathers (col premultiplied x16) ------
__global__ __launch_bounds__(256) void k_agg1(
    const unsigned short* __restrict__ h, const int* __restrict__ row_ptr,
    const int* __restrict__ col, const float* __restrict__ dinv,
    const float* __restrict__ bias, unsigned short* __restrict__ z, int n) {
    int node = blockIdx.x * 4 + (threadIdx.x >> 6);
    node = __builtin_amdgcn_readfirstlane(node);
    if (node >= n) return;
    int lane = threadIdx.x & 63;
    int q = lane >> 4, li = lane & 15;
    const uint4* hp = (const uint4*)h;  // 16 uint4 per row (128 ch fp16 = 256 B)
    float acc[8] = {0.f, 0.f, 0.f, 0.f, 0.f, 0.f, 0.f, 0.f};
    auto addrow = [&](uint4 v) {
        acc[0] += h2f(v.x); acc[1] += h2f(v.x >> 16);
        acc[2] += h2f(v.y); acc[3] += h2f(v.y >> 16);
        acc[4] += h2f(v.z); acc[5] += h2f(v.z >> 16);
        acc[6] += h2f(v.w); acc[7] += h2f(v.w >> 16);
    };
    if (q == 0) addrow(hp[(long)node * 16 + li]);  // self-loop once
    int rs = row_ptr[node], re = row_ptr[node + 1];
    int j = rs + q;
    for (; j + 12 < re; j += 16) {  // 4 gathers in flight per quarter
        int s0 = col[j], s1 = col[j + 4], s2 = col[j + 8], s3 = col[j + 12];
        uint4 v0 = hp[(long)s0 + li];
        uint4 v1 = hp[(long)s1 + li];
        uint4 v2 = hp[(long)s2 + li];
        uint4 v3 = hp[(long)s3 + li];
        addrow(v0); addrow(v1); addrow(v2); addrow(v3);
    }
    for (; j + 4 < re; j += 8) {    // 2 in flight
        int s0 = col[j], s1 = col[j + 4];
        uint4 v0 = hp[(long)s0 + li];
        uint4 v1 = hp[(long)s1 + li];
        addrow(v0); addrow(v1);
    }
    for (; j < re; j += 4) addrow(hp[(long)col[j] + li]);
#pragma unroll
    for (int k = 0; k < 8; ++k) {
        acc[k] += __shfl_xor(acc[k], 16);
        acc[k] += __shfl_xor(acc[k], 32);
    }
    if (q == 0) {
        float dv = dinv[node];
        const float4* bp = (const float4*)bias;
        float4 b0 = bp[li * 2], b1 = bp[li * 2 + 1];
        uint4 o;
        o.x = packh2(fmaxf(fmaf(acc[0], dv, b0.x), 0.f), fmaxf(fmaf(acc[1], dv, b0.y), 0.f));
        o.y = packh2(fmaxf(fmaf(acc[2], dv, b0.z), 0.f), fmaxf(fmaf(acc[3], dv, b0.w), 0.f));
        o.z = packh2(fmaxf(fmaf(acc[4], dv, b1.x), 0.f), fmaxf(fmaf(acc[5], dv, b1.y), 0.f));
        o.w = packh2(fmaxf(fmaf(acc[6], dv, b1.z), 0.f), fmaxf(fmaf(acc[7], dv, b1.w), 0.f));
        ((uint4*)z)[(long)node * 16 + li] = o;  // z1 fp16, [node][128]
    }
}

__global__ __launch_bounds__(256) void k_agg2(
    const unsigned short* __restrict__ h, const int* __restrict__ row_ptr,
    const int* __restrict__ col, const float* __restrict__ dinv,
    const float* __restrict__ bias, float* __restrict__ z, int n) {
    int node = blockIdx.x * 4 + (threadIdx.x >> 6);
    node = __builtin_amdgcn_readfirstlane(node);
    if (node >= n) return;
    int lane = threadIdx.x & 63;
    int q = lane >> 4, li = lane & 15;
    const uint2* hp = (const uint2*)h;  // 16 uint2 per row (64 ch fp16 = 128 B)
    float acc[4] = {0.f, 0.f, 0.f, 0.f};
    auto addrow = [&](uint2 v) {
        acc[0] += h2f(v.x); acc[1] += h2f(v.x >> 16);
        acc[2] += h2f(v.y); acc[3] += h2f(v.y >> 16);
    };
    if (q == 0) addrow(hp[(long)node * 16 + li]);  // self-loop
    int rs = row_ptr[node], re = row_ptr[node + 1];
    int j = rs + q;
    for (; j + 12 < re; j += 16) {
        int s0 = col[j], s1 = col[j + 4], s2 = col[j + 8], s3 = col[j + 12];
        uint2 v0 = hp[(long)s0 + li];
        uint2 v1 = hp[(long)s1 + li];
        uint2 v2 = hp[(long)s2 + li];
        uint2 v3 = hp[(long)s3 + li];
        addrow(v0); addrow(v1); addrow(v2); addrow(v3);
    }
    for (; j + 4 < re; j += 8) {
        int s0 = col[j], s1 = col[j + 4];
        uint2 v0 = hp[(long)s0 + li];
        uint2 v1 = hp[(long)s1 + li];
        addrow(v0); addrow(v1);
    }
    for (; j < re; j += 4) addrow(hp[(long)col[j] + li]);
#pragma unroll
    for (int k = 0; k < 4; ++k) {
        acc[k] += __shfl_xor(acc[k], 16);
        acc[k] += __shfl_xor(acc[k], 32);
    }
    if (q == 0) {
        float dv = dinv[node];
        float4 b = ((const float4*)bias)[li];
        float4 o;
        o.x = fmaf(acc[0], dv, b.x);
        o.y = fmaf(acc[1], dv, b.y);
        o.z = fmaf(acc[2], dv, b.z);
        o.w = fmaf(acc[3], dv, b.w);
        ((float4*)z)[(long)node * 16 + li] = o;
    }
}

// ---------------- decoder: 4 edges per wave (quarter-wave each, float4 per lane) ------
__global__ void k_dot(const float* __restrict__ z2, const int* __restrict__ es,
                      const int* __restrict__ ed, float* __restrict__ out, int L) {
    int gid = blockIdx.x * blockDim.x + threadIdx.x;
    int wid = gid >> 6;
    int lane = threadIdx.x & 63;
    int q = lane >> 4, li = lane & 15;
    int e = wid * 4 + q;
    if (e >= L) return;
    int a = es[e], b = ed[e];
    const float4* zp = (const float4*)z2;  // 16 float4 per row (64 ch fp32)
    float4 za = zp[(long)a * 16 + li];
    float4 zb = zp[(long)b * 16 + li];
    float v = za.x * zb.x + za.y * zb.y + za.z * zb.z + za.w * zb.w;
#pragma unroll
    for (int off = 8; off > 0; off >>= 1) v += __shfl_xor(v, off);  // within quarter
    if (li == 0) out[e] = v;
}

extern "C" void kernel_launch(void* const* d_in, const int* in_sizes, int n_in,
                              void* d_out, int out_size, void* d_ws, size_t ws_size,
                              hipStream_t stream) {
    const float* x = (const float*)d_in[0];
    const int* ei = (const int*)d_in[1];
    const int* eli = (const int*)d_in[2];
    const float* W1 = (const float*)d_in[3];
    const float* b1 = (const float*)d_in[4];
    const float* W2 = (const float*)d_in[5];
    const float* b2 = (const float*)d_in[6];
    float* out = (float*)d_out;

    const int N = in_sizes[0] / IN_C;  // 50000
    const int E = in_sizes[1] / 2;     // 800000
    const int L = in_sizes[2] / 2;     // 100000
    const int* src = ei;
    const int* dst = ei + E;
    const int* es = eli;
    const int* ed = eli + L;

    const int Npad = (N + 63) & ~63;
    const int Epad = (E + 3) & ~3;

    // workspace layout
    int* cnt = (int*)d_ws;             // Npad (also the fill cursor, consumed)
    int* row_ptr = cnt + Npad;         // Npad + 64
    int* bsum = row_ptr + Npad + 64;   // 256
    int* col = bsum + 256;             // Epad
    float* dinv = (float*)(col + Epad);                   // Npad
    unsigned short* h1s = (unsigned short*)(dinv + Npad); // N*128 fp16
    unsigned short* z1 = h1s + (long)N * HID_C;           // N*128 fp16
    unsigned short* h2s = h1s;                            // alias: h1s dead after agg1
    float* z2 = (float*)(z1 + (long)N * HID_C);           // N*64 fp32
    unsigned short* wt1_hi = (unsigned short*)(z2 + (long)N * OUT_C);  // 512*128
    unsigned short* wt1_lo = wt1_hi + IN_C * HID_C;
    unsigned short* wt2_hi = wt1_lo + IN_C * HID_C;                    // 128*64
    unsigned short* wt2_lo = wt2_hi + HID_C * OUT_C;

    const int TPB = 256;
    const int nb = (N + 255) / 256;

    // fused weight prep + cnt zeroing (one launch)
    const int PW = IN_C * HID_C + HID_C * OUT_C + Npad;
    k_prep_zero<<<(PW + TPB - 1) / TPB, TPB, 0, stream>>>(W1, wt1_hi, wt1_lo, W2, wt2_hi, wt2_lo, cnt, Npad);

    // CSR build + dinv
    k_count<<<(E + TPB - 1) / TPB, TPB, 0, stream>>>(dst, cnt, E);
    k_blocksum_dinv<<<nb, 256, 0, stream>>>(cnt, bsum, dinv, N);
    k_scanpartials<<<1, 256, 0, stream>>>(bsum, nb);
    k_scanfinal<<<nb, 256, 0, stream>>>(cnt, bsum, row_ptr, N, E);
    k_fill<<<(E + TPB - 1) / TPB, TPB, 0, stream>>>(src, dst, row_ptr, cnt, col, E);

    // layer 1 (8-wave GEMM: 782 blocks x 512 threads)
    k_gemm_mfma8<<<(N + 63) / 64, 512, 0, stream>>>(x, wt1_hi, wt1_lo, dinv, h1s, N);
    k_agg1<<<(N + 3) / 4, 256, 0, stream>>>(h1s, row_ptr, col, dinv, b1, z1, N);

    // layer 2 (8-wave GEMM, A = z1 fp16)
    k_gemm_mfma8_l2<<<(N + 63) / 64, 512, 0, stream>>>(z1, wt2_hi, wt2_lo, dinv, h2s, N);
    k_agg2<<<(N + 3) / 4, 256, 0, stream>>>(h2s, row_ptr, col, dinv, b2, z2, N);

    // decoder (4 edges/wave)
    k_dot<<<((long)((L + 3) / 4) * 64 + TPB - 1) / TPB, TPB, 0, stream>>>(z2, es, ed, out, L);
}